// Round 1
// baseline (2086.957 us; speedup 1.0000x reference)
//
#include <hip/hip_runtime.h>
#include <math.h>
#include <float.h>

#define BB 32
#define DD 128
#define LL 1024
#define NN 32768
#define NE 8192
#define XSZ 4194304
#define OUT_OFF_Q     4194304
#define OUT_OFF_SCAL  8388608
#define OUT_OFF_KSUM  8388612
#define OUT_OFF_KELEM 9437188

__device__ inline float waveSum(float v){
  #pragma unroll
  for (int o = 32; o > 0; o >>= 1) v += __shfl_down(v, o, 64);
  return v;
}
__device__ inline double waveSumD(double v){
  #pragma unroll
  for (int o = 32; o > 0; o >>= 1) v += __shfl_down(v, o, 64);
  return v;
}

// s2[j] = sum_d e[j][d]^2 ; one wave per row
__global__ __launch_bounds__(256) void s2_kernel(const float* __restrict__ e,
                                                 float* __restrict__ s2){
  int t = threadIdx.x;
  int j = blockIdx.x * 4 + (t >> 6);
  int lane = t & 63;
  float a = e[j * DD + lane];
  float b = e[j * DD + 64 + lane];
  float v = a * a + b * b;
  v = waveSum(v);
  if (lane == 0) s2[j] = v;
}

// global sum / sumsq of x (for prenorm)
__global__ __launch_bounds__(256) void stats_kernel(const float* __restrict__ x,
                                                    float* __restrict__ accs){
  int gid = blockIdx.x * 256 + threadIdx.x;
  float4 v = ((const float4*)x)[gid];
  float s = v.x + v.y + v.z + v.w;
  float q = v.x*v.x + v.y*v.y + v.z*v.z + v.w*v.w;
  s = waveSum(s); q = waveSum(q);
  __shared__ float ss[4], qq[4];
  int w = threadIdx.x >> 6;
  if ((threadIdx.x & 63) == 0){ ss[w] = s; qq[w] = q; }
  __syncthreads();
  if (threadIdx.x == 0){
    atomicAdd(&accs[0], ss[0]+ss[1]+ss[2]+ss[3]);
    atomicAdd(&accs[1], qq[0]+qq[1]+qq[2]+qq[3]);
  }
}

// fused distance GEMM + argmin. Block = 64 tokens; stream all 8192 codes in
// 64-code tiles. Track m = s2[j] - 2*dot (s1 added at the end).
__global__ __launch_bounds__(256, 2) void argmin_kernel(const float* __restrict__ x,
      const float* __restrict__ e, const float* __restrict__ s2,
      int* __restrict__ idxo, float* __restrict__ mindo)
{
  __shared__ float tokS[64][132];   // [token][k], +4 pad: 16B-aligned rows
  __shared__ float embS[64][132];   // [code][k]
  __shared__ float s2s[64];
  __shared__ float s1s[64];
  __shared__ float redm[64 * 16];
  __shared__ int   redi[64 * 16];

  int t  = threadIdx.x;
  int n0 = blockIdx.x * 64;         // 1024 % 64 == 0 -> single batch b per block
  int b  = n0 >> 10;
  int l0 = n0 & 1023;
  const float* xb = x + (size_t)b * (DD * LL);

  int col = t & 63;
  int wv  = t >> 6;
  #pragma unroll
  for (int r = 0; r < 32; ++r) {           // transpose x[b][d][l] -> tokS[l][d]
    int d = r * 4 + wv;
    tokS[col][d] = xb[d * LL + l0 + col];  // coalesced read; one-time LDS write
  }
  __syncthreads();
  if (t < 64) {                            // s1 per token
    float s = 0.f;
    #pragma unroll 4
    for (int k = 0; k < DD; ++k) { float v = tokS[t][k]; s = fmaf(v, v, s); }
    s1s[t] = s;
  }

  int tm = t & 15;                         // token group (4 tokens)
  int tn = t >> 4;                         // code group  (4 codes)
  float m[4]; int mi[4];
  #pragma unroll
  for (int i = 0; i < 4; ++i){ m[i] = FLT_MAX; mi[i] = 0; }

  for (int tile = 0; tile < NE / 64; ++tile) {
    int j0 = tile * 64;
    __syncthreads();                       // embS consumed by previous iter
    #pragma unroll
    for (int r = 0; r < 32; ++r) {         // coalesced load, conflict-free write
      int lin = r * 256 + t;
      int j = lin >> 7;
      int k = lin & 127;
      embS[j][k] = e[(j0 + j) * DD + k];
    }
    if (t < 64) s2s[t] = s2[j0 + t];
    __syncthreads();

    float acc[4][4];
    #pragma unroll
    for (int i = 0; i < 4; ++i)
      #pragma unroll
      for (int jj = 0; jj < 4; ++jj) acc[i][jj] = 0.f;

    #pragma unroll 4
    for (int k4 = 0; k4 < 32; ++k4) {
      float4 av[4], bv[4];
      #pragma unroll
      for (int i = 0; i < 4; ++i)
        av[i] = *reinterpret_cast<const float4*>(&tokS[tm * 4 + i][k4 * 4]);
      #pragma unroll
      for (int jj = 0; jj < 4; ++jj)
        bv[jj] = *reinterpret_cast<const float4*>(&embS[tn * 4 + jj][k4 * 4]);
      #pragma unroll
      for (int i = 0; i < 4; ++i)
        #pragma unroll
        for (int jj = 0; jj < 4; ++jj) {
          acc[i][jj] = fmaf(av[i].x, bv[jj].x, acc[i][jj]);
          acc[i][jj] = fmaf(av[i].y, bv[jj].y, acc[i][jj]);
          acc[i][jj] = fmaf(av[i].z, bv[jj].z, acc[i][jj]);
          acc[i][jj] = fmaf(av[i].w, bv[jj].w, acc[i][jj]);
        }
    }
    #pragma unroll
    for (int jj = 0; jj < 4; ++jj) {
      float s2v = s2s[tn * 4 + jj];
      int j = j0 + tn * 4 + jj;
      #pragma unroll
      for (int i = 0; i < 4; ++i) {
        float cand = fmaf(-2.f, acc[i][jj], s2v);
        if (cand < m[i]) { m[i] = cand; mi[i] = j; }  // strict <: first-min kept
      }
    }
  }

  #pragma unroll
  for (int i = 0; i < 4; ++i){
    redm[(tm * 4 + i) * 16 + tn] = m[i];
    redi[(tm * 4 + i) * 16 + tn] = mi[i];
  }
  __syncthreads();
  if (t < 64) {
    float bm = FLT_MAX; int bi = 0;
    #pragma unroll
    for (int g = 0; g < 16; ++g) {
      float v = redm[t * 16 + g]; int ji = redi[t * 16 + g];
      if (v < bm || (v == bm && ji < bi)) { bm = v; bi = ji; }
    }
    idxo[n0 + t]  = bi;
    mindo[n0 + t] = s1s[t] + bm;
  }
}

// gather quantized, STE out, commit-loss partial, k_sum/k_elem scatter
__global__ __launch_bounds__(256) void out_kernel(const float* __restrict__ x,
   const float* __restrict__ e, const int* __restrict__ idx,
   float* __restrict__ out, float* __restrict__ quant,
   float* __restrict__ ksum, float* __restrict__ kelem, float* __restrict__ accs)
{
  int gid = blockIdx.x * 256 + threadIdx.x;
  int l = gid & 1023;
  int d = (gid >> 10) & 127;
  int b = gid >> 17;
  int n = (b << 10) + l;
  int j = idx[n];
  float xv = x[gid];
  float q  = e[j * DD + d];
  float df = q - xv;
  out[gid]   = xv + df;   // match ref: x + (q - x)
  quant[gid] = q;
  atomicAdd(&ksum[j * DD + d], xv);
  if (d == 0) atomicAdd(&kelem[j], 1.0f);
  float c = df * df;
  c = waveSum(c);
  __shared__ float cs[4];
  if ((threadIdx.x & 63) == 0) cs[threadIdx.x >> 6] = c;
  __syncthreads();
  if (threadIdx.x == 0) atomicAdd(&accs[2], cs[0]+cs[1]+cs[2]+cs[3]);
}

__global__ __launch_bounds__(256) void final_kernel(const float* __restrict__ mind,
    const float* __restrict__ kelem, const float* __restrict__ accs,
    float* __restrict__ scal)
{
  int t = threadIdx.x;
  double fs = 0.0;
  for (int i = t; i < NN; i += 256) {
    float v = mind[i];
    if (!isnan(v)) fs += (double)v;        // nan_to_num
  }
  double es = 0.0;
  for (int i = t; i < NE; i += 256) {
    float p = kelem[i] * (1.0f / NN);
    es += (double)(p * logf(p + 1e-8f));
  }
  fs = waveSumD(fs); es = waveSumD(es);
  __shared__ double fr[4], er[4];
  if ((t & 63) == 0){ fr[t >> 6] = fs; er[t >> 6] = es; }
  __syncthreads();
  if (t == 0) {
    double fit = (fr[0]+fr[1]+fr[2]+fr[3]) / (double)NN;
    double ent = -(er[0]+er[1]+er[2]+er[3]);
    float sum = accs[0], sq = accs[1], commit = accs[2];
    double mu  = (double)sum / (double)XSZ;
    double var = (double)sq / (double)XSZ - mu * mu;
    if (var < 0) var = 0;
    scal[0] = (float)(0.25 * (double)commit / (double)XSZ);  // loss (BETA=0.25)
    scal[1] = (float)fit;
    scal[2] = (float)sqrt(var);                              // prenorm
    scal[3] = (float)ent;                                    // entropy
  }
}

extern "C" void kernel_launch(void* const* d_in, const int* in_sizes, int n_in,
                              void* d_out, int out_size, void* d_ws, size_t ws_size,
                              hipStream_t stream)
{
  const float* x = (const float*)d_in[0];
  const float* e = (const float*)d_in[1];
  float* out   = (float*)d_out;
  float* quant = out + OUT_OFF_Q;
  float* scal  = out + OUT_OFF_SCAL;
  float* ksum  = out + OUT_OFF_KSUM;
  float* kelem = out + OUT_OFF_KELEM;

  // ws layout: s2[8192]f @0 | idx[32768]i @32768B | mind[32768]f @163840B | accs @294912B
  float* s2   = (float*)d_ws;
  int*   idx  = (int*)((char*)d_ws + 32768);
  float* mind = (float*)((char*)d_ws + 163840);
  float* accs = (float*)((char*)d_ws + 294912);

  hipMemsetAsync(accs, 0, 16, stream);
  hipMemsetAsync(ksum, 0, (size_t)(1048576 + 8192) * 4, stream);

  s2_kernel   <<<NE / 4,     256, 0, stream>>>(e, s2);
  stats_kernel<<<XSZ / 1024, 256, 0, stream>>>(x, accs);
  argmin_kernel<<<NN / 64,   256, 0, stream>>>(x, e, s2, idx, mind);
  out_kernel  <<<XSZ / 256,  256, 0, stream>>>(x, e, idx, out, quant, ksum, kelem, accs);
  final_kernel<<<1,          256, 0, stream>>>(mind, kelem, accs, scal);
}

// Round 2
// 883.411 us; speedup vs baseline: 2.3624x; 2.3624x over previous
//
#include <hip/hip_runtime.h>
#include <math.h>
#include <float.h>

#define BB 32
#define DD 128
#define LL 1024
#define NN 32768
#define NE 8192
#define XSZ 4194304
#define OUT_OFF_Q     4194304
#define OUT_OFF_SCAL  8388608
#define OUT_OFF_KSUM  8388612
#define OUT_OFF_KELEM 9437188

typedef unsigned int u32;
typedef unsigned short u16;
typedef short bf16x8 __attribute__((ext_vector_type(8)));
typedef float f32x4 __attribute__((ext_vector_type(4)));

__device__ inline float waveSum(float v){
  #pragma unroll
  for (int o = 32; o > 0; o >>= 1) v += __shfl_down(v, o, 64);
  return v;
}
__device__ inline double waveSumD(double v){
  #pragma unroll
  for (int o = 32; o > 0; o >>= 1) v += __shfl_down(v, o, 64);
  return v;
}

__device__ inline u16 bf16_rn(float f){
  u32 u = __float_as_uint(f);
  u32 r = u + 0x7FFFu + ((u >> 16) & 1u);
  return (u16)(r >> 16);
}

// ---------- s2[j] = sum_d e[j][d]^2 ----------
__global__ __launch_bounds__(256) void s2_kernel(const float* __restrict__ e,
                                                 float* __restrict__ s2){
  int t = threadIdx.x;
  int j = blockIdx.x * 4 + (t >> 6);
  int lane = t & 63;
  float a = e[j * DD + lane];
  float b = e[j * DD + 64 + lane];
  float v = a * a + b * b;
  v = waveSum(v);
  if (lane == 0) s2[j] = v;
}

// ---------- prep: split -2*e into swizzled bf16 hi/lo planes ----------
// LDS image byte = row*256 + (kbyte ^ ((row&7)<<4)); stored pre-swizzled in
// global so linear global_load_lds staging lands swizzled (rule #21).
__global__ __launch_bounds__(256) void prep_split(const float* __restrict__ e,
                                                  u32* __restrict__ eh,
                                                  u32* __restrict__ el){
  int gid = blockIdx.x * 256 + threadIdx.x;   // one dword (2 elems) per thread
  int row = gid >> 6;
  int kd  = gid & 63;
  float2 ev = *reinterpret_cast<const float2*>(&e[row * DD + kd * 2]);
  float v0 = -2.f * ev.x, v1 = -2.f * ev.y;
  u16 h0 = bf16_rn(v0);
  u16 h1 = bf16_rn(v1);
  u16 l0 = bf16_rn(v0 - __uint_as_float((u32)h0 << 16));
  u16 l1 = bf16_rn(v1 - __uint_as_float((u32)h1 << 16));
  int dst = row * 64 + (kd ^ ((row & 7) << 2));
  eh[dst] = (u32)h0 | ((u32)h1 << 16);
  el[dst] = (u32)l0 | ((u32)l1 << 16);
}

// ---------- global sum / sumsq of x (prenorm) ----------
__global__ __launch_bounds__(256) void stats_kernel(const float* __restrict__ x,
                                                    float* __restrict__ accs){
  int gid = blockIdx.x * 256 + threadIdx.x;
  float4 v = ((const float4*)x)[gid];
  float s = v.x + v.y + v.z + v.w;
  float q = v.x*v.x + v.y*v.y + v.z*v.z + v.w*v.w;
  s = waveSum(s); q = waveSum(q);
  __shared__ float ss[4], qq[4];
  int w = threadIdx.x >> 6;
  if ((threadIdx.x & 63) == 0){ ss[w] = s; qq[w] = q; }
  __syncthreads();
  if (threadIdx.x == 0){
    atomicAdd(&accs[0], ss[0]+ss[1]+ss[2]+ss[3]);
    atomicAdd(&accs[1], qq[0]+qq[1]+qq[2]+qq[3]);
  }
}

// ---------- MFMA argmin: dist = s2[j] - 2*dot via acc-init + bf16x3 split ----
// Block: 4 waves x 32 tokens (shared); codes split across waves.
// A (codes) from swizzled LDS; B (tokens) in registers; C col=token,row=code.
__device__ inline void stage16k(const u16* __restrict__ g, u16* l, int t){
  #pragma unroll
  for (int i = 0; i < 4; ++i){
    __builtin_amdgcn_global_load_lds(
      (const __attribute__((address_space(1))) u32*)(g + (i*256 + t)*8),
      (__attribute__((address_space(3))) u32*)(l + i*2048 + (t & ~63)*8),
      16, 0, 0);
  }
}

__global__ __launch_bounds__(256, 2) void argmin_mfma(
    const float* __restrict__ x,
    const u16* __restrict__ eh, const u16* __restrict__ el,
    const float* __restrict__ s2,
    int* __restrict__ idx1o, int* __restrict__ idx2o)
{
  __shared__ __align__(16) u32 ehs[2][4096];   // 2 x 16KB (64 codes x 128 bf16)
  __shared__ __align__(16) u32 els[2][4096];
  __shared__ __align__(16) float s2s[2][64];
  __shared__ float mm1[512]; __shared__ int mi1[512];
  __shared__ float mm2[512]; __shared__ int mi2[512];

  int t  = threadIdx.x;
  int w  = t >> 6;          // wave 0..3 (code-slab within each staged tile)
  int l  = t & 63;
  int lr = l & 15;          // A-row / C-col / B-col sub-index
  int lg = l >> 4;          // k-group, C row group

  int n0 = blockIdx.x * 32;
  int b  = n0 >> 10;
  int l0 = n0 & 1023;
  const float* xb = x + (size_t)b * (DD * LL);

  // ---- B fragments (tokens) in registers, bf16 hi/lo split ----
  bf16x8 Bh[2][4], Bl[2][4];
  #pragma unroll
  for (int ct = 0; ct < 2; ++ct){
    int tok = l0 + ct*16 + lr;
    #pragma unroll
    for (int kt = 0; kt < 4; ++kt){
      #pragma unroll
      for (int j = 0; j < 8; ++j){
        float v = xb[(kt*32 + lg*8 + j) * LL + tok];
        u16 hb = bf16_rn(v);
        float hf = __uint_as_float((u32)hb << 16);
        u16 lb = bf16_rn(v - hf);
        Bh[ct][kt][j] = (short)hb;
        Bl[ct][kt][j] = (short)lb;
      }
    }
  }

  float m1[2] = {FLT_MAX, FLT_MAX}, m2[2] = {FLT_MAX, FLT_MAX};
  int   i1[2] = {0, 0},             i2[2] = {0, 0};

  stage16k(eh, (u16*)&ehs[0][0], t);
  stage16k(el, (u16*)&els[0][0], t);
  if (t < 64) s2s[0][t] = s2[t];
  __syncthreads();

  int rowLoc = w*16 + lr;
  int sw = (rowLoc & 7) << 4;
  const char* baseH0 = (const char*)&ehs[0][0];
  const char* baseL0 = (const char*)&els[0][0];
  const char* baseH1 = (const char*)&ehs[1][0];
  const char* baseL1 = (const char*)&els[1][0];

  for (int it = 0; it < NE/64; ++it){
    int bb = it & 1;
    if (it + 1 < NE/64){
      stage16k(eh + (size_t)(it+1)*8192, (u16*)&ehs[bb^1][0], t);
      stage16k(el + (size_t)(it+1)*8192, (u16*)&els[bb^1][0], t);
      if (t < 64) s2s[bb^1][t] = s2[(it+1)*64 + t];
    }
    const char* bh = bb ? baseH1 : baseH0;
    const char* bl = bb ? baseL1 : baseL0;

    f32x4 s2v = *(const f32x4*)&s2s[bb][w*16 + lg*4];
    f32x4 acc0 = s2v, acc1 = s2v;
    #pragma unroll
    for (int kt = 0; kt < 4; ++kt){
      int boff = rowLoc*256 + ((kt*64 + lg*16) ^ sw);
      bf16x8 Ah = *(const bf16x8*)(bh + boff);
      bf16x8 Al = *(const bf16x8*)(bl + boff);
      acc0 = __builtin_amdgcn_mfma_f32_16x16x32_bf16(Ah, Bh[0][kt], acc0, 0,0,0);
      acc0 = __builtin_amdgcn_mfma_f32_16x16x32_bf16(Ah, Bl[0][kt], acc0, 0,0,0);
      acc0 = __builtin_amdgcn_mfma_f32_16x16x32_bf16(Al, Bh[0][kt], acc0, 0,0,0);
      acc1 = __builtin_amdgcn_mfma_f32_16x16x32_bf16(Ah, Bh[1][kt], acc1, 0,0,0);
      acc1 = __builtin_amdgcn_mfma_f32_16x16x32_bf16(Ah, Bl[1][kt], acc1, 0,0,0);
      acc1 = __builtin_amdgcn_mfma_f32_16x16x32_bf16(Al, Bh[1][kt], acc1, 0,0,0);
    }
    int jbase = it*64 + w*16 + lg*4;
    #pragma unroll
    for (int r = 0; r < 4; ++r){
      int j = jbase + r;
      {
        float cand = acc0[r];
        bool c1 = cand < m1[0];
        bool c2 = cand < m2[0];
        i2[0] = c1 ? i1[0] : (c2 ? j : i2[0]);
        m2[0] = fminf(fmaxf(cand, m1[0]), m2[0]);
        i1[0] = c1 ? j : i1[0];
        m1[0] = c1 ? cand : m1[0];
      }
      {
        float cand = acc1[r];
        bool c1 = cand < m1[1];
        bool c2 = cand < m2[1];
        i2[1] = c1 ? i1[1] : (c2 ? j : i2[1]);
        m2[1] = fminf(fmaxf(cand, m1[1]), m2[1]);
        i1[1] = c1 ? j : i1[1];
        m1[1] = c1 ? cand : m1[1];
      }
    }
    __syncthreads();
  }

  // ---- merge 16 partial top-2 states per token ----
  #pragma unroll
  for (int ct = 0; ct < 2; ++ct){
    int sidx = (ct*16 + lr)*16 + w*4 + lg;   // state order == ascending j order
    mm1[sidx] = m1[ct]; mi1[sidx] = i1[ct];
    mm2[sidx] = m2[ct]; mi2[sidx] = i2[ct];
  }
  __syncthreads();
  if (t < 32){
    float M1 = FLT_MAX, M2 = FLT_MAX; int I1 = 0x7fffffff, I2 = 0x7fffffff;
    for (int s = 0; s < 16; ++s){
      float c = mm1[t*16 + s]; int j = mi1[t*16 + s];
      if (c < M1 || (c == M1 && j < I1)) { M2 = M1; I2 = I1; M1 = c; I1 = j; }
      else if (c < M2) { M2 = c; I2 = j; }
      float c2 = mm2[t*16 + s]; int j2 = mi2[t*16 + s];
      if (c2 < M1 || (c2 == M1 && j2 < I1)) { M2 = M1; I2 = I1; M1 = c2; I1 = j2; }
      else if (c2 < M2) { M2 = c2; I2 = j2; }
    }
    idx1o[n0 + t] = I1;
    idx2o[n0 + t] = I2;
  }
}

// ---------- exact fp32 re-rank of the two candidates; fit partial sum ----
__global__ __launch_bounds__(256) void fixup_kernel(const float* __restrict__ x,
    const float* __restrict__ e, const float* __restrict__ s2,
    const int* __restrict__ idx1, const int* __restrict__ idx2,
    int* __restrict__ idxo, float* __restrict__ accs)
{
  int n = blockIdx.x * 256 + threadIdx.x;
  int b = n >> 10, l = n & 1023;
  const float* xb = x + (size_t)b * (DD * LL);
  int a = idx1[n], c = idx2[n];
  float s1 = 0.f, d1 = 0.f, d2 = 0.f;
  #pragma unroll 4
  for (int k = 0; k < DD; ++k){
    float xv = xb[k * LL + l];
    s1 = fmaf(xv, xv, s1);
    d1 = fmaf(xv, e[a * DD + k], d1);
    d2 = fmaf(xv, e[c * DD + k], d2);
  }
  float da = s1 + s2[a] - 2.f * d1;
  float db = s1 + s2[c] - 2.f * d2;
  int j; float d;
  if (db < da || (db == da && c < a)) { j = c; d = db; }
  else                                { j = a; d = da; }
  idxo[n] = j;
  float fs = waveSum(d);
  if ((threadIdx.x & 63) == 0) atomicAdd(&accs[3], fs);
}

// ---------- gather quantized, STE out, commit-loss, k_sum/k_elem scatter ----
__global__ __launch_bounds__(256) void out_kernel(const float* __restrict__ x,
   const float* __restrict__ e, const int* __restrict__ idx,
   float* __restrict__ out, float* __restrict__ quant,
   float* __restrict__ ksum, float* __restrict__ kelem, float* __restrict__ accs)
{
  int gid = blockIdx.x * 256 + threadIdx.x;
  int l = gid & 1023;
  int d = (gid >> 10) & 127;
  int b = gid >> 17;
  int n = (b << 10) + l;
  int j = idx[n];
  float xv = x[gid];
  float q  = e[j * DD + d];
  float df = q - xv;
  out[gid]   = xv + df;
  quant[gid] = q;
  atomicAdd(&ksum[j * DD + d], xv);
  if (d == 0) atomicAdd(&kelem[j], 1.0f);
  float cc = df * df;
  cc = waveSum(cc);
  __shared__ float cs[4];
  if ((threadIdx.x & 63) == 0) cs[threadIdx.x >> 6] = cc;
  __syncthreads();
  if (threadIdx.x == 0) atomicAdd(&accs[2], cs[0]+cs[1]+cs[2]+cs[3]);
}

// ---------- entropy + scalar finalize ----------
__global__ __launch_bounds__(256) void final_kernel(const float* __restrict__ kelem,
    const float* __restrict__ accs, float* __restrict__ scal)
{
  int t = threadIdx.x;
  double es = 0.0;
  for (int i = t; i < NE; i += 256){
    float p = kelem[i] * (1.0f / NN);
    es += (double)(p * logf(p + 1e-8f));
  }
  es = waveSumD(es);
  __shared__ double er[4];
  if ((t & 63) == 0) er[t >> 6] = es;
  __syncthreads();
  if (t == 0){
    double ent = -(er[0]+er[1]+er[2]+er[3]);
    float sum = accs[0], sq = accs[1], commit = accs[2], fitsum = accs[3];
    double mu  = (double)sum / (double)XSZ;
    double var = (double)sq / (double)XSZ - mu * mu;
    if (var < 0) var = 0;
    scal[0] = (float)(0.25 * (double)commit / (double)XSZ);
    scal[1] = (float)((double)fitsum / (double)NN);
    scal[2] = (float)sqrt(var);
    scal[3] = (float)ent;
  }
}

extern "C" void kernel_launch(void* const* d_in, const int* in_sizes, int n_in,
                              void* d_out, int out_size, void* d_ws, size_t ws_size,
                              hipStream_t stream)
{
  const float* x = (const float*)d_in[0];
  const float* e = (const float*)d_in[1];
  float* out   = (float*)d_out;
  float* quant = out + OUT_OFF_Q;
  float* scal  = out + OUT_OFF_SCAL;
  float* ksum  = out + OUT_OFF_KSUM;
  float* kelem = out + OUT_OFF_KELEM;

  // ws: eh 2MB | el 2MB | s2 32KB | idx1 128KB | idx2 128KB | idxf 128KB | accs
  char* wsb = (char*)d_ws;
  u32*   eh   = (u32*)(wsb);
  u32*   el   = (u32*)(wsb + 2097152);
  float* s2   = (float*)(wsb + 4194304);
  int*   idx1 = (int*)(wsb + 4227072);
  int*   idx2 = (int*)(wsb + 4358144);
  int*   idxf = (int*)(wsb + 4489216);
  float* accs = (float*)(wsb + 4620288);

  hipMemsetAsync(accs, 0, 32, stream);
  hipMemsetAsync(ksum, 0, (size_t)(1048576 + 8192) * 4, stream);

  s2_kernel   <<<NE / 4,        256, 0, stream>>>(e, s2);
  prep_split  <<<NE * 64 / 256, 256, 0, stream>>>(e, eh, el);
  stats_kernel<<<XSZ / 1024,    256, 0, stream>>>(x, accs);
  argmin_mfma <<<NN / 32,       256, 0, stream>>>(x, (const u16*)eh, (const u16*)el,
                                                  s2, idx1, idx2);
  fixup_kernel<<<NN / 256,      256, 0, stream>>>(x, e, s2, idx1, idx2, idxf, accs);
  out_kernel  <<<XSZ / 256,     256, 0, stream>>>(x, e, idxf, out, quant,
                                                  ksum, kelem, accs);
  final_kernel<<<1,             256, 0, stream>>>(kelem, accs, scal);
}

// Round 3
// 632.870 us; speedup vs baseline: 3.2976x; 1.3959x over previous
//
#include <hip/hip_runtime.h>
#include <math.h>
#include <float.h>

#define BB 32
#define DD 128
#define LL 1024
#define NN 32768
#define NE 8192
#define XSZ 4194304
#define OUT_OFF_Q     4194304
#define OUT_OFF_SCAL  8388608
#define OUT_OFF_KSUM  8388612
#define OUT_OFF_KELEM 9437188

typedef unsigned int u32;
typedef unsigned short u16;
typedef short bf16x8 __attribute__((ext_vector_type(8)));
typedef float f32x4 __attribute__((ext_vector_type(4)));

__device__ inline float waveSum(float v){
  #pragma unroll
  for (int o = 32; o > 0; o >>= 1) v += __shfl_down(v, o, 64);
  return v;
}
__device__ inline double waveSumD(double v){
  #pragma unroll
  for (int o = 32; o > 0; o >>= 1) v += __shfl_down(v, o, 64);
  return v;
}

__device__ inline u16 bf16_rn(float f){
  u32 u = __float_as_uint(f);
  u32 r = u + 0x7FFFu + ((u >> 16) & 1u);
  return (u16)(r >> 16);
}

// ---------- s2[j] = sum_d e[j][d]^2 ----------
__global__ __launch_bounds__(256) void s2_kernel(const float* __restrict__ e,
                                                 float* __restrict__ s2){
  int t = threadIdx.x;
  int j = blockIdx.x * 4 + (t >> 6);
  int lane = t & 63;
  float a = e[j * DD + lane];
  float b = e[j * DD + 64 + lane];
  float v = a * a + b * b;
  v = waveSum(v);
  if (lane == 0) s2[j] = v;
}

// ---------- prep: split -2*e into swizzled bf16 hi/lo planes ----------
__global__ __launch_bounds__(256) void prep_split(const float* __restrict__ e,
                                                  u32* __restrict__ eh,
                                                  u32* __restrict__ el){
  int gid = blockIdx.x * 256 + threadIdx.x;   // one dword (2 elems) per thread
  int row = gid >> 6;
  int kd  = gid & 63;
  float2 ev = *reinterpret_cast<const float2*>(&e[row * DD + kd * 2]);
  float v0 = -2.f * ev.x, v1 = -2.f * ev.y;
  u16 h0 = bf16_rn(v0);
  u16 h1 = bf16_rn(v1);
  u16 l0 = bf16_rn(v0 - __uint_as_float((u32)h0 << 16));
  u16 l1 = bf16_rn(v1 - __uint_as_float((u32)h1 << 16));
  int dst = row * 64 + (kd ^ ((row & 7) << 2));
  eh[dst] = (u32)h0 | ((u32)h1 << 16);
  el[dst] = (u32)l0 | ((u32)l1 << 16);
}

// ---------- MFMA argmin with packed int-key top-2 ----------
__device__ inline void stage16k(const u16* __restrict__ g, u16* l, int t){
  #pragma unroll
  for (int i = 0; i < 4; ++i){
    __builtin_amdgcn_global_load_lds(
      (const __attribute__((address_space(1))) u32*)(g + (i*256 + t)*8),
      (__attribute__((address_space(3))) u32*)(l + i*2048 + (t & ~63)*8),
      16, 0, 0);
  }
}

__global__ __launch_bounds__(256, 2) void argmin_mfma(
    const float* __restrict__ x,
    const u16* __restrict__ eh, const u16* __restrict__ el,
    const float* __restrict__ s2,
    int* __restrict__ idx1o, int* __restrict__ idx2o)
{
  __shared__ __align__(16) u32 ehs[2][4096];
  __shared__ __align__(16) u32 els[2][4096];
  __shared__ __align__(16) float s2s[2][64];
  __shared__ int kk1[512];
  __shared__ int kk2[512];

  int t  = threadIdx.x;
  int w  = t >> 6;
  int l  = t & 63;
  int lr = l & 15;
  int lg = l >> 4;

  int n0 = blockIdx.x * 32;
  int b  = n0 >> 10;
  int l0 = n0 & 1023;
  const float* xb = x + (size_t)b * (DD * LL);

  bf16x8 Bh[2][4], Bl[2][4];
  #pragma unroll
  for (int ct = 0; ct < 2; ++ct){
    int tok = l0 + ct*16 + lr;
    #pragma unroll
    for (int kt = 0; kt < 4; ++kt){
      #pragma unroll
      for (int j = 0; j < 8; ++j){
        float v = xb[(kt*32 + lg*8 + j) * LL + tok];
        u16 hb = bf16_rn(v);
        float hf = __uint_as_float((u32)hb << 16);
        u16 lb = bf16_rn(v - hf);
        Bh[ct][kt][j] = (short)hb;
        Bl[ct][kt][j] = (short)lb;
      }
    }
  }

  int k1[2] = {0x7fffffff, 0x7fffffff};
  int k2[2] = {0x7fffffff, 0x7fffffff};

  stage16k(eh, (u16*)&ehs[0][0], t);
  stage16k(el, (u16*)&els[0][0], t);
  if (t < 64) s2s[0][t] = s2[t];
  __syncthreads();

  int rowLoc = w*16 + lr;
  int sw = (rowLoc & 7) << 4;
  const char* baseH0 = (const char*)&ehs[0][0];
  const char* baseL0 = (const char*)&els[0][0];
  const char* baseH1 = (const char*)&ehs[1][0];
  const char* baseL1 = (const char*)&els[1][0];

  for (int it = 0; it < NE/64; ++it){
    int bb = it & 1;
    if (it + 1 < NE/64){
      stage16k(eh + (size_t)(it+1)*8192, (u16*)&ehs[bb^1][0], t);
      stage16k(el + (size_t)(it+1)*8192, (u16*)&els[bb^1][0], t);
      if (t < 64) s2s[bb^1][t] = s2[(it+1)*64 + t];
    }
    const char* bh = bb ? baseH1 : baseH0;
    const char* bl = bb ? baseL1 : baseL0;

    f32x4 s2v = *(const f32x4*)&s2s[bb][w*16 + lg*4];
    f32x4 acc0 = s2v, acc1 = s2v;
    #pragma unroll
    for (int kt = 0; kt < 4; ++kt){
      int boff = rowLoc*256 + ((kt*64 + lg*16) ^ sw);
      bf16x8 Ah = *(const bf16x8*)(bh + boff);
      bf16x8 Al = *(const bf16x8*)(bl + boff);
      acc0 = __builtin_amdgcn_mfma_f32_16x16x32_bf16(Ah, Bh[0][kt], acc0, 0,0,0);
      acc0 = __builtin_amdgcn_mfma_f32_16x16x32_bf16(Ah, Bl[0][kt], acc0, 0,0,0);
      acc0 = __builtin_amdgcn_mfma_f32_16x16x32_bf16(Al, Bh[0][kt], acc0, 0,0,0);
      acc1 = __builtin_amdgcn_mfma_f32_16x16x32_bf16(Ah, Bh[1][kt], acc1, 0,0,0);
      acc1 = __builtin_amdgcn_mfma_f32_16x16x32_bf16(Ah, Bl[1][kt], acc1, 0,0,0);
      acc1 = __builtin_amdgcn_mfma_f32_16x16x32_bf16(Al, Bh[1][kt], acc1, 0,0,0);
    }
    // packed key: ((int)(256*m + 65536) << 13) | j ; monotone (m in [-80,350]),
    // quantum 1/256 << bf16-split error; tie -> smaller j (= first occurrence)
    int jbase = it*64 + w*16 + lg*4;
    #pragma unroll
    for (int r = 0; r < 4; ++r){
      {
        int key = (((int)fmaf(acc0[r], 256.f, 65536.f)) << 13) | (jbase + r);
        int mx = max(key, k1[0]);
        k2[0] = min(mx, k2[0]);
        k1[0] = min(key, k1[0]);
      }
      {
        int key = (((int)fmaf(acc1[r], 256.f, 65536.f)) << 13) | (jbase + r);
        int mx = max(key, k1[1]);
        k2[1] = min(mx, k2[1]);
        k1[1] = min(key, k1[1]);
      }
    }
    __syncthreads();
  }

  #pragma unroll
  for (int ct = 0; ct < 2; ++ct){
    int sidx = (ct*16 + lr)*16 + w*4 + lg;
    kk1[sidx] = k1[ct];
    kk2[sidx] = k2[ct];
  }
  __syncthreads();
  if (t < 32){
    int K1 = 0x7fffffff, K2 = 0x7fffffff;
    #pragma unroll 4
    for (int s = 0; s < 16; ++s){
      int a = kk1[t*16 + s], b2 = kk2[t*16 + s];
      int mx = max(a, K1);  K2 = min(mx, K2);  K1 = min(a, K1);
      mx = max(b2, K1);     K2 = min(mx, K2);  K1 = min(b2, K1);
    }
    idx1o[n0 + t] = K1 & 8191;
    idx2o[n0 + t] = K2 & 8191;
  }
}

// ---------- exact fp32 re-rank + fit + prenorm stats + histogram ----------
__global__ __launch_bounds__(256) void fixup_kernel(const float* __restrict__ x,
    const float* __restrict__ e, const float* __restrict__ s2,
    const int* __restrict__ idx1, const int* __restrict__ idx2,
    int* __restrict__ idxf, int* __restrict__ cnt, float* __restrict__ accs)
{
  int n = blockIdx.x * 256 + threadIdx.x;
  int b = n >> 10, l = n & 1023;
  const float* xb = x + (size_t)b * (DD * LL) + l;
  int a = idx1[n], c = idx2[n];
  const float4* ea = (const float4*)&e[a * DD];
  const float4* ec = (const float4*)&e[c * DD];
  float s1 = 0.f, sx = 0.f, d1 = 0.f, d2 = 0.f;
  #pragma unroll 4
  for (int k4 = 0; k4 < 32; ++k4){
    float4 va = ea[k4], vc = ec[k4];
    float x0 = xb[(k4*4+0) * LL];
    float x1 = xb[(k4*4+1) * LL];
    float x2 = xb[(k4*4+2) * LL];
    float x3 = xb[(k4*4+3) * LL];
    s1 = fmaf(x0,x0, fmaf(x1,x1, fmaf(x2,x2, fmaf(x3,x3, s1))));
    sx += x0 + x1 + x2 + x3;
    d1 = fmaf(x0,va.x, fmaf(x1,va.y, fmaf(x2,va.z, fmaf(x3,va.w, d1))));
    d2 = fmaf(x0,vc.x, fmaf(x1,vc.y, fmaf(x2,vc.z, fmaf(x3,vc.w, d2))));
  }
  float da = s1 + s2[a] - 2.f * d1;
  float db = s1 + s2[c] - 2.f * d2;
  int j; float dd;
  if (db < da || (db == da && c < a)) { j = c; dd = db; }
  else                                { j = a; dd = da; }
  idxf[n] = j;
  atomicAdd(&cnt[j], 1);
  dd = waveSum(dd); s1 = waveSum(s1); sx = waveSum(sx);
  if ((threadIdx.x & 63) == 0){
    atomicAdd(&accs[3], dd);
    atomicAdd(&accs[1], s1);
    atomicAdd(&accs[0], sx);
  }
}

// ---------- single-block prefix scan: cnt -> cursor(start), kelem ----------
__global__ __launch_bounds__(1024) void prefix_kernel(const int* __restrict__ cnt,
    int* __restrict__ cursor, float* __restrict__ kelem)
{
  __shared__ int sc[1024];
  int t = threadIdx.x;
  int c[8]; int s = 0;
  #pragma unroll
  for (int i = 0; i < 8; ++i){ c[i] = cnt[t*8 + i]; s += c[i]; }
  sc[t] = s;
  __syncthreads();
  for (int off = 1; off < 1024; off <<= 1){
    int v = sc[t];
    int u = (t >= off) ? sc[t - off] : 0;
    __syncthreads();
    sc[t] = v + u;
    __syncthreads();
  }
  int base = t ? sc[t-1] : 0;
  #pragma unroll
  for (int i = 0; i < 8; ++i){
    cursor[t*8 + i] = base;
    kelem[t*8 + i] = (float)c[i];
    base += c[i];
  }
}

// ---------- scatter token ids into code-sorted order ----------
__global__ __launch_bounds__(256) void scatter_kernel(const int* __restrict__ idxf,
    int* __restrict__ cursor, int* __restrict__ order)
{
  int n = blockIdx.x * 256 + threadIdx.x;
  int j = idxf[n];
  int p = atomicAdd(&cursor[j], 1);
  order[p] = n;
}

// ---------- atomic-free ksum: one wave per code, gather token columns ----
__global__ __launch_bounds__(256) void ksum_kernel(const float* __restrict__ x,
    const int* __restrict__ order, const int* __restrict__ cnt,
    const int* __restrict__ cursor, float* __restrict__ ksum)
{
  int w = threadIdx.x >> 6, lane = threadIdx.x & 63;
  int j = blockIdx.x * 4 + w;
  int c = cnt[j];
  int st = cursor[j] - c;          // cursor is end after scatter
  float a0 = 0.f, a1 = 0.f;
  for (int k = 0; k < c; ++k){
    int n = order[st + k];
    int b = n >> 10, l = n & 1023;
    const float* xb = x + (size_t)b * (DD * LL) + l;
    a0 += xb[lane * LL];
    a1 += xb[(lane + 64) * LL];
  }
  ksum[j * DD + lane]      = a0;
  ksum[j * DD + 64 + lane] = a1;
}

// ---------- gather quantized, STE out, commit loss (no scatter atomics) ----
__global__ __launch_bounds__(256) void out_kernel(const float* __restrict__ x,
   const float* __restrict__ e, const int* __restrict__ idxf,
   float* __restrict__ out, float* __restrict__ quant, float* __restrict__ accs)
{
  int gid = blockIdx.x * 256 + threadIdx.x;    // one float4 per thread
  int l4 = gid & 255;
  int d  = (gid >> 8) & 127;
  int b  = gid >> 15;
  int n0 = (b << 10) + l4 * 4;
  int4 jv = *(const int4*)&idxf[n0];
  float4 xv = *(const float4*)&x[(size_t)gid * 4];
  float4 q;
  q.x = e[jv.x * DD + d];
  q.y = e[jv.y * DD + d];
  q.z = e[jv.z * DD + d];
  q.w = e[jv.w * DD + d];
  float4 df = make_float4(q.x - xv.x, q.y - xv.y, q.z - xv.z, q.w - xv.w);
  float4 ov = make_float4(xv.x + df.x, xv.y + df.y, xv.z + df.z, xv.w + df.w);
  *(float4*)&out[(size_t)gid * 4]   = ov;
  *(float4*)&quant[(size_t)gid * 4] = q;
  float cc = df.x*df.x + df.y*df.y + df.z*df.z + df.w*df.w;
  cc = waveSum(cc);
  __shared__ float cs[4];
  if ((threadIdx.x & 63) == 0) cs[threadIdx.x >> 6] = cc;
  __syncthreads();
  if (threadIdx.x == 0) atomicAdd(&accs[2], cs[0]+cs[1]+cs[2]+cs[3]);
}

// ---------- entropy + scalar finalize ----------
__global__ __launch_bounds__(256) void final_kernel(const float* __restrict__ kelem,
    const float* __restrict__ accs, float* __restrict__ scal)
{
  int t = threadIdx.x;
  double es = 0.0;
  for (int i = t; i < NE; i += 256){
    float p = kelem[i] * (1.0f / NN);
    es += (double)(p * logf(p + 1e-8f));
  }
  es = waveSumD(es);
  __shared__ double er[4];
  if ((t & 63) == 0) er[t >> 6] = es;
  __syncthreads();
  if (t == 0){
    double ent = -(er[0]+er[1]+er[2]+er[3]);
    float sum = accs[0], sq = accs[1], commit = accs[2], fitsum = accs[3];
    double mu  = (double)sum / (double)XSZ;
    double var = (double)sq / (double)XSZ - mu * mu;
    if (var < 0) var = 0;
    scal[0] = (float)(0.25 * (double)commit / (double)XSZ);
    scal[1] = (float)((double)fitsum / (double)NN);
    scal[2] = (float)sqrt(var);
    scal[3] = (float)ent;
  }
}

extern "C" void kernel_launch(void* const* d_in, const int* in_sizes, int n_in,
                              void* d_out, int out_size, void* d_ws, size_t ws_size,
                              hipStream_t stream)
{
  const float* x = (const float*)d_in[0];
  const float* e = (const float*)d_in[1];
  float* out   = (float*)d_out;
  float* quant = out + OUT_OFF_Q;
  float* scal  = out + OUT_OFF_SCAL;
  float* ksum  = out + OUT_OFF_KSUM;
  float* kelem = out + OUT_OFF_KELEM;

  // ws: eh 2MB | el 2MB | s2 32KB | idx1 128KB | idx2 128KB | idxf 128KB |
  //     cnt 32KB | cursor 32KB | order 128KB | accs 64B
  char* wsb = (char*)d_ws;
  u32*   eh     = (u32*)(wsb);
  u32*   el     = (u32*)(wsb + 2097152);
  float* s2     = (float*)(wsb + 4194304);
  int*   idx1   = (int*)(wsb + 4227072);
  int*   idx2   = (int*)(wsb + 4358144);
  int*   idxf   = (int*)(wsb + 4489216);
  int*   cnt    = (int*)(wsb + 4620288);
  int*   cursor = (int*)(wsb + 4653056);
  int*   order  = (int*)(wsb + 4685824);
  float* accs   = (float*)(wsb + 4816896);

  hipMemsetAsync(accs, 0, 32, stream);
  hipMemsetAsync(cnt, 0, NE * 4, stream);

  s2_kernel    <<<NE / 4,        256, 0, stream>>>(e, s2);
  prep_split   <<<NE * 64 / 256, 256, 0, stream>>>(e, eh, el);
  argmin_mfma  <<<NN / 32,       256, 0, stream>>>(x, (const u16*)eh, (const u16*)el,
                                                   s2, idx1, idx2);
  fixup_kernel <<<NN / 256,      256, 0, stream>>>(x, e, s2, idx1, idx2, idxf, cnt, accs);
  prefix_kernel<<<1,            1024, 0, stream>>>(cnt, cursor, kelem);
  scatter_kernel<<<NN / 256,     256, 0, stream>>>(idxf, cursor, order);
  ksum_kernel  <<<NE / 4,        256, 0, stream>>>(x, order, cnt, cursor, ksum);
  out_kernel   <<<XSZ / 1024,    256, 0, stream>>>(x, e, idxf, out, quant, accs);
  final_kernel <<<1,             256, 0, stream>>>(kelem, accs, scal);
}

// Round 4
// 493.037 us; speedup vs baseline: 4.2329x; 1.2836x over previous
//
#include <hip/hip_runtime.h>
#include <math.h>
#include <float.h>

#define BB 32
#define DD 128
#define LL 1024
#define NN 32768
#define NE 8192
#define XSZ 4194304
#define OUT_OFF_Q     4194304
#define OUT_OFF_SCAL  8388608
#define OUT_OFF_KSUM  8388612
#define OUT_OFF_KELEM 9437188

typedef unsigned int u32;
typedef unsigned short u16;
typedef short bf16x8 __attribute__((ext_vector_type(8)));
typedef float f32x4 __attribute__((ext_vector_type(4)));

__device__ inline float waveSum(float v){
  #pragma unroll
  for (int o = 32; o > 0; o >>= 1) v += __shfl_down(v, o, 64);
  return v;
}
__device__ inline double waveSumD(double v){
  #pragma unroll
  for (int o = 32; o > 0; o >>= 1) v += __shfl_down(v, o, 64);
  return v;
}

__device__ inline u16 bf16_rn(float f){
  u32 u = __float_as_uint(f);
  u32 r = u + 0x7FFFu + ((u >> 16) & 1u);
  return (u16)(r >> 16);
}

// ---------- prep: s2k = 65536 + 256*s2, planes = bf16 split of -32*e ------
// (prescale folds the 256x key quantization into the MFMA: (-32e)*(16x) = -512 e.x)
__global__ __launch_bounds__(256) void prep_kernel(const float* __restrict__ e,
    u32* __restrict__ eh, u32* __restrict__ el, float* __restrict__ s2k)
{
  int t = threadIdx.x;
  int row = blockIdx.x * 4 + (t >> 6);
  int kd  = t & 63;
  float2 ev = *reinterpret_cast<const float2*>(&e[row * DD + kd * 2]);
  float sq = ev.x * ev.x + ev.y * ev.y;
  sq = waveSum(sq);
  if (kd == 0) s2k[row] = 65536.f + 256.f * sq;
  float v0 = -32.f * ev.x, v1 = -32.f * ev.y;
  u16 h0 = bf16_rn(v0);
  u16 h1 = bf16_rn(v1);
  u16 l0 = bf16_rn(v0 - __uint_as_float((u32)h0 << 16));
  u16 l1 = bf16_rn(v1 - __uint_as_float((u32)h1 << 16));
  int dst = row * 64 + (kd ^ ((row & 7) << 2));   // pre-swizzled for LDS image
  eh[dst] = (u32)h0 | ((u32)h1 << 16);
  el[dst] = (u32)l0 | ((u32)l1 << 16);
}

// ---------- MFMA argmin: 64 tokens/block, packed int-key top-2 ----------
__device__ inline void stage16k(const u16* __restrict__ g, u16* l, int t){
  #pragma unroll
  for (int i = 0; i < 4; ++i){
    __builtin_amdgcn_global_load_lds(
      (const __attribute__((address_space(1))) u32*)(g + (i*256 + t)*8),
      (__attribute__((address_space(3))) u32*)(l + i*2048 + (t & ~63)*8),
      16, 0, 0);
  }
}

__global__ __launch_bounds__(256, 2) void argmin_mfma(
    const float* __restrict__ x,
    const u16* __restrict__ eh, const u16* __restrict__ el,
    const float* __restrict__ s2k,
    int* __restrict__ idx1o, int* __restrict__ idx2o)
{
  __shared__ __align__(16) u32 ehs[2][4096];   // 2 x 16KB
  __shared__ __align__(16) u32 els[2][4096];
  __shared__ __align__(16) float s2s[2][64];
  __shared__ int kk1[1024];
  __shared__ int kk2[1024];

  int t  = threadIdx.x;
  int w  = t >> 6;
  int l  = t & 63;
  int lr = l & 15;
  int lg = l >> 4;

  int n0 = blockIdx.x * 64;
  int b  = n0 >> 10;
  int l0 = n0 & 1023;
  const float* xb = x + (size_t)b * (DD * LL);

  // B fragments: 64 tokens (4 ct-blocks), bf16 hi/lo of 16*x  -> 128 VGPR
  bf16x8 Bh[4][4], Bl[4][4];
  #pragma unroll
  for (int ct = 0; ct < 4; ++ct){
    int tok = l0 + ct*16 + lr;
    #pragma unroll
    for (int kt = 0; kt < 4; ++kt){
      #pragma unroll
      for (int j = 0; j < 8; ++j){
        float v = 16.f * xb[(kt*32 + lg*8 + j) * LL + tok];
        u16 hb = bf16_rn(v);
        float hf = __uint_as_float((u32)hb << 16);
        u16 lb = bf16_rn(v - hf);
        Bh[ct][kt][j] = (short)hb;
        Bl[ct][kt][j] = (short)lb;
      }
    }
  }

  int k1[4], k2[4];
  #pragma unroll
  for (int ct = 0; ct < 4; ++ct){ k1[ct] = 0x7fffffff; k2[ct] = 0x7fffffff; }

  stage16k(eh, (u16*)&ehs[0][0], t);
  stage16k(el, (u16*)&els[0][0], t);
  if (t < 64) s2s[0][t] = s2k[t];
  __syncthreads();

  int rowLoc = w*16 + lr;
  int sw = (rowLoc & 7) << 4;

  for (int it = 0; it < NE/64; ++it){
    int bb = it & 1;
    if (it + 1 < NE/64){
      stage16k(eh + (size_t)(it+1)*8192, (u16*)&ehs[bb^1][0], t);
      stage16k(el + (size_t)(it+1)*8192, (u16*)&els[bb^1][0], t);
      if (t < 64) s2s[bb^1][t] = s2k[(it+1)*64 + t];
    }
    const char* bh = (const char*)&ehs[bb][0];
    const char* bl = (const char*)&els[bb][0];

    // clustered LDS burst: all A fragments for this wave's 16-code slab
    bf16x8 Ah[4], Al[4];
    #pragma unroll
    for (int kt = 0; kt < 4; ++kt){
      int boff = rowLoc*256 + ((kt*64 + lg*16) ^ sw);
      Ah[kt] = *(const bf16x8*)(bh + boff);
      Al[kt] = *(const bf16x8*)(bl + boff);
    }

    f32x4 s2v = *(const f32x4*)&s2s[bb][w*16 + lg*4];
    f32x4 acc[4];
    #pragma unroll
    for (int ct = 0; ct < 4; ++ct) acc[ct] = s2v;

    // MFMA burst (48), dependent chain distance 4
    __builtin_amdgcn_s_setprio(1);
    #pragma unroll
    for (int kt = 0; kt < 4; ++kt){
      #pragma unroll
      for (int ct = 0; ct < 4; ++ct)
        acc[ct] = __builtin_amdgcn_mfma_f32_16x16x32_bf16(Ah[kt], Bh[ct][kt], acc[ct], 0,0,0);
      #pragma unroll
      for (int ct = 0; ct < 4; ++ct)
        acc[ct] = __builtin_amdgcn_mfma_f32_16x16x32_bf16(Ah[kt], Bl[ct][kt], acc[ct], 0,0,0);
      #pragma unroll
      for (int ct = 0; ct < 4; ++ct)
        acc[ct] = __builtin_amdgcn_mfma_f32_16x16x32_bf16(Al[kt], Bh[ct][kt], acc[ct], 0,0,0);
    }
    __builtin_amdgcn_s_setprio(0);

    // key = (int(65536 + 256*(s2-2ex)) << 13) | j ; top-2 = 3 int min/max
    int jbase = it*64 + w*16 + lg*4;
    #pragma unroll
    for (int ct = 0; ct < 4; ++ct){
      #pragma unroll
      for (int r = 0; r < 4; ++r){
        int key = (((int)acc[ct][r]) << 13) | (jbase + r);
        int mx = max(key, k1[ct]);
        k2[ct] = min(mx, k2[ct]);
        k1[ct] = min(key, k1[ct]);
      }
    }
    __syncthreads();
  }

  #pragma unroll
  for (int ct = 0; ct < 4; ++ct){
    int sidx = (ct*16 + lr)*16 + w*4 + lg;
    kk1[sidx] = k1[ct];
    kk2[sidx] = k2[ct];
  }
  __syncthreads();
  if (t < 64){
    int K1 = 0x7fffffff, K2 = 0x7fffffff;
    #pragma unroll 4
    for (int s = 0; s < 16; ++s){
      int a = kk1[t*16 + s], b2 = kk2[t*16 + s];
      int mx = max(a, K1);  K2 = min(mx, K2);  K1 = min(a, K1);
      mx = max(b2, K1);     K2 = min(mx, K2);  K1 = min(b2, K1);
    }
    idx1o[n0 + t] = K1 & 8191;
    idx2o[n0 + t] = K2 & 8191;
  }
}

// ---------- exact fp32 re-rank + fit + prenorm stats + histogram ----------
__global__ __launch_bounds__(256) void fixup_kernel(const float* __restrict__ x,
    const float* __restrict__ e,
    const int* __restrict__ idx1, const int* __restrict__ idx2,
    int* __restrict__ idxf, int* __restrict__ cnt, float* __restrict__ accs)
{
  int n = blockIdx.x * 256 + threadIdx.x;
  int b = n >> 10, l = n & 1023;
  const float* xb = x + (size_t)b * (DD * LL) + l;
  int a = idx1[n], c = idx2[n];
  const float4* ea = (const float4*)&e[a * DD];
  const float4* ec = (const float4*)&e[c * DD];
  float s1 = 0.f, sx = 0.f, d1 = 0.f, d2 = 0.f, sa = 0.f, sc2 = 0.f;
  #pragma unroll 4
  for (int k4 = 0; k4 < 32; ++k4){
    float4 va = ea[k4], vc = ec[k4];
    float x0 = xb[(k4*4+0) * LL];
    float x1 = xb[(k4*4+1) * LL];
    float x2 = xb[(k4*4+2) * LL];
    float x3 = xb[(k4*4+3) * LL];
    s1 = fmaf(x0,x0, fmaf(x1,x1, fmaf(x2,x2, fmaf(x3,x3, s1))));
    sx += x0 + x1 + x2 + x3;
    d1 = fmaf(x0,va.x, fmaf(x1,va.y, fmaf(x2,va.z, fmaf(x3,va.w, d1))));
    d2 = fmaf(x0,vc.x, fmaf(x1,vc.y, fmaf(x2,vc.z, fmaf(x3,vc.w, d2))));
    sa = fmaf(va.x,va.x, fmaf(va.y,va.y, fmaf(va.z,va.z, fmaf(va.w,va.w, sa))));
    sc2= fmaf(vc.x,vc.x, fmaf(vc.y,vc.y, fmaf(vc.z,vc.z, fmaf(vc.w,vc.w, sc2))));
  }
  float da = s1 + sa  - 2.f * d1;
  float db = s1 + sc2 - 2.f * d2;
  int j; float dd;
  if (db < da || (db == da && c < a)) { j = c; dd = db; }
  else                                { j = a; dd = da; }
  idxf[n] = j;
  atomicAdd(&cnt[j], 1);
  dd = waveSum(dd); s1 = waveSum(s1); sx = waveSum(sx);
  if ((threadIdx.x & 63) == 0){
    atomicAdd(&accs[3], dd);
    atomicAdd(&accs[1], s1);
    atomicAdd(&accs[0], sx);
  }
}

// ---------- single-block prefix scan: cnt -> cursor(start), kelem ----------
__global__ __launch_bounds__(1024) void prefix_kernel(const int* __restrict__ cnt,
    int* __restrict__ cursor, float* __restrict__ kelem)
{
  __shared__ int sc[1024];
  int t = threadIdx.x;
  int c[8]; int s = 0;
  #pragma unroll
  for (int i = 0; i < 8; ++i){ c[i] = cnt[t*8 + i]; s += c[i]; }
  sc[t] = s;
  __syncthreads();
  for (int off = 1; off < 1024; off <<= 1){
    int v = sc[t];
    int u = (t >= off) ? sc[t - off] : 0;
    __syncthreads();
    sc[t] = v + u;
    __syncthreads();
  }
  int base = t ? sc[t-1] : 0;
  #pragma unroll
  for (int i = 0; i < 8; ++i){
    cursor[t*8 + i] = base;
    kelem[t*8 + i] = (float)c[i];
    base += c[i];
  }
}

// ---------- scatter token ids into code-sorted order ----------
__global__ __launch_bounds__(256) void scatter_kernel(const int* __restrict__ idxf,
    int* __restrict__ cursor, int* __restrict__ order)
{
  int n = blockIdx.x * 256 + threadIdx.x;
  int j = idxf[n];
  int p = atomicAdd(&cursor[j], 1);
  order[p] = n;
}

// ---------- transpose x[b][d][l] -> xT[token][d] (coalesced both sides) ----
__global__ __launch_bounds__(256) void transpose_kernel(const float* __restrict__ x,
    float* __restrict__ xT)
{
  __shared__ float tile[64][137];   // 137: odd dword stride, 2-way max
  int t = threadIdx.x;
  int b  = blockIdx.x >> 4;
  int l0 = (blockIdx.x & 15) << 6;
  const float* xb = x + (size_t)b * (DD * LL);
  #pragma unroll
  for (int rep = 0; rep < 32; ++rep){
    int idx = rep * 256 + t;
    int d = idx >> 6, ll = idx & 63;
    tile[ll][d] = xb[d * LL + l0 + ll];
  }
  __syncthreads();
  int n0 = (b << 10) + l0;
  #pragma unroll
  for (int rep = 0; rep < 8; ++rep){
    int idx = rep * 256 + t;
    int row = idx >> 5, c4 = idx & 31;
    float4 v;
    v.x = tile[row][c4*4+0]; v.y = tile[row][c4*4+1];
    v.z = tile[row][c4*4+2]; v.w = tile[row][c4*4+3];
    *(float4*)&xT[(size_t)(n0 + row) * DD + c4*4] = v;
  }
}

// ---------- atomic-free ksum from xT (contiguous 512B per member) ----------
__global__ __launch_bounds__(256) void ksum_xt_kernel(const float* __restrict__ xT,
    const int* __restrict__ order, const int* __restrict__ cnt,
    const int* __restrict__ cursor, float* __restrict__ ksum)
{
  int w = threadIdx.x >> 6, lane = threadIdx.x & 63;
  int j = blockIdx.x * 4 + w;
  int c = cnt[j];
  int st = cursor[j] - c;          // cursor is end after scatter
  float a0 = 0.f, a1 = 0.f;
  for (int k = 0; k < c; ++k){
    int n = order[st + k];
    const float* xr = xT + (size_t)n * DD;
    a0 += xr[lane];
    a1 += xr[64 + lane];
  }
  ksum[j * DD + lane]      = a0;
  ksum[j * DD + 64 + lane] = a1;
}

// ---------- fallback ksum reading x columns (if ws too small for xT) ------
__global__ __launch_bounds__(256) void ksum_kernel(const float* __restrict__ x,
    const int* __restrict__ order, const int* __restrict__ cnt,
    const int* __restrict__ cursor, float* __restrict__ ksum)
{
  int w = threadIdx.x >> 6, lane = threadIdx.x & 63;
  int j = blockIdx.x * 4 + w;
  int c = cnt[j];
  int st = cursor[j] - c;
  float a0 = 0.f, a1 = 0.f;
  for (int k = 0; k < c; ++k){
    int n = order[st + k];
    int b = n >> 10, l = n & 1023;
    const float* xb = x + (size_t)b * (DD * LL) + l;
    a0 += xb[lane * LL];
    a1 += xb[(lane + 64) * LL];
  }
  ksum[j * DD + lane]      = a0;
  ksum[j * DD + 64 + lane] = a1;
}

// ---------- gather quantized, STE out, commit loss ----------
__global__ __launch_bounds__(256) void out_kernel(const float* __restrict__ x,
   const float* __restrict__ e, const int* __restrict__ idxf,
   float* __restrict__ out, float* __restrict__ quant, float* __restrict__ accs)
{
  int gid = blockIdx.x * 256 + threadIdx.x;    // one float4 per thread
  int l4 = gid & 255;
  int d  = (gid >> 8) & 127;
  int b  = gid >> 15;
  int n0 = (b << 10) + l4 * 4;
  int4 jv = *(const int4*)&idxf[n0];
  float4 xv = *(const float4*)&x[(size_t)gid * 4];
  float4 q;
  q.x = e[jv.x * DD + d];
  q.y = e[jv.y * DD + d];
  q.z = e[jv.z * DD + d];
  q.w = e[jv.w * DD + d];
  float4 df = make_float4(q.x - xv.x, q.y - xv.y, q.z - xv.z, q.w - xv.w);
  float4 ov = make_float4(xv.x + df.x, xv.y + df.y, xv.z + df.z, xv.w + df.w);
  *(float4*)&out[(size_t)gid * 4]   = ov;
  *(float4*)&quant[(size_t)gid * 4] = q;
  float cc = df.x*df.x + df.y*df.y + df.z*df.z + df.w*df.w;
  cc = waveSum(cc);
  __shared__ float cs[4];
  if ((threadIdx.x & 63) == 0) cs[threadIdx.x >> 6] = cc;
  __syncthreads();
  if (threadIdx.x == 0) atomicAdd(&accs[2], cs[0]+cs[1]+cs[2]+cs[3]);
}

// ---------- entropy + scalar finalize ----------
__global__ __launch_bounds__(256) void final_kernel(const float* __restrict__ kelem,
    const float* __restrict__ accs, float* __restrict__ scal)
{
  int t = threadIdx.x;
  double es = 0.0;
  for (int i = t; i < NE; i += 256){
    float p = kelem[i] * (1.0f / NN);
    es += (double)(p * logf(p + 1e-8f));
  }
  es = waveSumD(es);
  __shared__ double er[4];
  if ((t & 63) == 0) er[t >> 6] = es;
  __syncthreads();
  if (t == 0){
    double ent = -(er[0]+er[1]+er[2]+er[3]);
    float sum = accs[0], sq = accs[1], commit = accs[2], fitsum = accs[3];
    double mu  = (double)sum / (double)XSZ;
    double var = (double)sq / (double)XSZ - mu * mu;
    if (var < 0) var = 0;
    scal[0] = (float)(0.25 * (double)commit / (double)XSZ);
    scal[1] = (float)((double)fitsum / (double)NN);
    scal[2] = (float)sqrt(var);
    scal[3] = (float)ent;
  }
}

extern "C" void kernel_launch(void* const* d_in, const int* in_sizes, int n_in,
                              void* d_out, int out_size, void* d_ws, size_t ws_size,
                              hipStream_t stream)
{
  const float* x = (const float*)d_in[0];
  const float* e = (const float*)d_in[1];
  float* out   = (float*)d_out;
  float* quant = out + OUT_OFF_Q;
  float* scal  = out + OUT_OFF_SCAL;
  float* ksum  = out + OUT_OFF_KSUM;
  float* kelem = out + OUT_OFF_KELEM;

  // ws: eh 2MB | el 2MB | s2k 32KB | idx1/idx2/idxf 128KB ea | cnt/cursor 32KB |
  //     order 128KB | accs | xT 16MB @ 5MB
  char* wsb = (char*)d_ws;
  u32*   eh     = (u32*)(wsb);
  u32*   el     = (u32*)(wsb + 2097152);
  float* s2k    = (float*)(wsb + 4194304);
  int*   idx1   = (int*)(wsb + 4227072);
  int*   idx2   = (int*)(wsb + 4358144);
  int*   idxf   = (int*)(wsb + 4489216);
  int*   cnt    = (int*)(wsb + 4620288);
  int*   cursor = (int*)(wsb + 4653056);
  int*   order  = (int*)(wsb + 4685824);
  float* accs   = (float*)(wsb + 4816896);
  float* xT     = (float*)(wsb + 5242880);
  bool useXT = ws_size >= (size_t)(5242880 + 16777216);

  hipMemsetAsync(accs, 0, 32, stream);
  hipMemsetAsync(cnt, 0, NE * 4, stream);

  prep_kernel   <<<NE / 4,     256, 0, stream>>>(e, eh, el, s2k);
  argmin_mfma   <<<NN / 64,    256, 0, stream>>>(x, (const u16*)eh, (const u16*)el,
                                                 s2k, idx1, idx2);
  fixup_kernel  <<<NN / 256,   256, 0, stream>>>(x, e, idx1, idx2, idxf, cnt, accs);
  prefix_kernel <<<1,         1024, 0, stream>>>(cnt, cursor, kelem);
  scatter_kernel<<<NN / 256,   256, 0, stream>>>(idxf, cursor, order);
  if (useXT){
    transpose_kernel<<<BB * 16, 256, 0, stream>>>(x, xT);
    ksum_xt_kernel  <<<NE / 4,  256, 0, stream>>>(xT, order, cnt, cursor, ksum);
  } else {
    ksum_kernel     <<<NE / 4,  256, 0, stream>>>(x, order, cnt, cursor, ksum);
  }
  out_kernel    <<<XSZ / 1024, 256, 0, stream>>>(x, e, idxf, out, quant, accs);
  final_kernel  <<<1,          256, 0, stream>>>(kelem, accs, scal);
}

// Round 5
// 465.999 us; speedup vs baseline: 4.4785x; 1.0580x over previous
//
#include <hip/hip_runtime.h>
#include <math.h>
#include <float.h>

#define BB 32
#define DD 128
#define LL 1024
#define NN 32768
#define NE 8192
#define XSZ 4194304
#define OUT_OFF_Q     4194304
#define OUT_OFF_SCAL  8388608
#define OUT_OFF_KSUM  8388612
#define OUT_OFF_KELEM 9437188

typedef unsigned int u32;
typedef unsigned short u16;
typedef short bf16x8 __attribute__((ext_vector_type(8)));
typedef float f32x4 __attribute__((ext_vector_type(4)));

__device__ inline float waveSum(float v){
  #pragma unroll
  for (int o = 32; o > 0; o >>= 1) v += __shfl_down(v, o, 64);
  return v;
}
__device__ inline double waveSumD(double v){
  #pragma unroll
  for (int o = 32; o > 0; o >>= 1) v += __shfl_down(v, o, 64);
  return v;
}

__device__ inline u16 bf16_rn(float f){
  u32 u = __float_as_uint(f);
  u32 r = u + 0x7FFFu + ((u >> 16) & 1u);
  return (u16)(r >> 16);
}

// ---------- prep: s2k = 65536 + 256*s2; planes = bf16 split of -32*e ------
// Fragment-linear layout: element (row r in 16-code tile T, k) at
//   u16 idx  T*2048 + kt*512 + (lg*16 + r)*8 + j   (k = kt*32 + lg*8 + j)
// so an A-fragment load is one fully-coalesced dwordx4 (64 lanes x 16B = 1KB).
__global__ __launch_bounds__(256) void prep_kernel(const float* __restrict__ e,
    u32* __restrict__ eh, u32* __restrict__ el, float* __restrict__ s2k)
{
  int t = threadIdx.x;
  int row = blockIdx.x * 4 + (t >> 6);
  int kd  = t & 63;                       // dword pair: k = 2kd, 2kd+1
  float2 ev = *reinterpret_cast<const float2*>(&e[row * DD + kd * 2]);
  float sq = ev.x * ev.x + ev.y * ev.y;
  sq = waveSum(sq);
  if (kd == 0) s2k[row] = 65536.f + 256.f * sq;
  float v0 = -32.f * ev.x, v1 = -32.f * ev.y;
  u16 h0 = bf16_rn(v0);
  u16 h1 = bf16_rn(v1);
  u16 l0 = bf16_rn(v0 - __uint_as_float((u32)h0 << 16));
  u16 l1 = bf16_rn(v1 - __uint_as_float((u32)h1 << 16));
  int k  = kd * 2;
  int kt = k >> 5, lg = (k >> 3) & 3, jh = (k & 7) >> 1;
  int T  = row >> 4, r = row & 15;
  int dst = T*1024 + kt*256 + (lg*16 + r)*4 + jh;
  eh[dst] = (u32)h0 | ((u32)h1 << 16);
  el[dst] = (u32)l0 | ((u32)l1 << 16);
}

// ---------- MFMA argmin: direct global->reg A-path, no LDS, no barriers ----
__device__ __forceinline__ void load_tile(const u32* __restrict__ ehp,
    const u32* __restrict__ elp, int T, bf16x8 (&Ah)[4], bf16x8 (&Al)[4])
{
  #pragma unroll
  for (int kt = 0; kt < 4; ++kt){
    Ah[kt] = *(const bf16x8*)(ehp + (size_t)T*4096 + kt*256);
    Al[kt] = *(const bf16x8*)(elp + (size_t)T*4096 + kt*256);
  }
}

__device__ __forceinline__ void compute_tile(
    const bf16x8 (&Ah)[4], const bf16x8 (&Al)[4],
    const bf16x8 (&Bh)[4][4], const bf16x8 (&Bl)[4][4],
    f32x4 s2v, int jbase, int (&k1)[4], int (&k2)[4])
{
  f32x4 acc[4];
  #pragma unroll
  for (int ct = 0; ct < 4; ++ct) acc[ct] = s2v;
  __builtin_amdgcn_s_setprio(1);
  #pragma unroll
  for (int kt = 0; kt < 4; ++kt){
    #pragma unroll
    for (int ct = 0; ct < 4; ++ct)
      acc[ct] = __builtin_amdgcn_mfma_f32_16x16x32_bf16(Ah[kt], Bh[ct][kt], acc[ct], 0,0,0);
    #pragma unroll
    for (int ct = 0; ct < 4; ++ct)
      acc[ct] = __builtin_amdgcn_mfma_f32_16x16x32_bf16(Ah[kt], Bl[ct][kt], acc[ct], 0,0,0);
    #pragma unroll
    for (int ct = 0; ct < 4; ++ct)
      acc[ct] = __builtin_amdgcn_mfma_f32_16x16x32_bf16(Al[kt], Bh[ct][kt], acc[ct], 0,0,0);
  }
  __builtin_amdgcn_s_setprio(0);
  // key = (int(65536 + 256*(s2-2ex)) << 13) | j ; top-2 = 3 int min/max
  #pragma unroll
  for (int ct = 0; ct < 4; ++ct){
    #pragma unroll
    for (int r = 0; r < 4; ++r){
      int key = (((int)acc[ct][r]) << 13) | (jbase + r);
      int mx = max(key, k1[ct]);
      k2[ct] = min(mx, k2[ct]);
      k1[ct] = min(key, k1[ct]);
    }
  }
}

__global__ __launch_bounds__(256, 2) void argmin_mfma(
    const float* __restrict__ x,
    const u32* __restrict__ eh, const u32* __restrict__ el,
    const f32x4* __restrict__ s2k4,
    int* __restrict__ idx1o, int* __restrict__ idx2o)
{
  __shared__ int kk1[1024];
  __shared__ int kk2[1024];

  int t  = threadIdx.x;
  int w  = t >> 6;
  int l  = t & 63;
  int lr = l & 15;
  int lg = l >> 4;

  int n0 = blockIdx.x * 64;
  int b  = n0 >> 10;
  int l0 = n0 & 1023;
  const float* xb = x + (size_t)b * (DD * LL);

  // B fragments: 64 tokens (4 ct-blocks), bf16 hi/lo of 16*x
  bf16x8 Bh[4][4], Bl[4][4];
  #pragma unroll
  for (int ct = 0; ct < 4; ++ct){
    int tok = l0 + ct*16 + lr;
    #pragma unroll
    for (int kt = 0; kt < 4; ++kt){
      #pragma unroll
      for (int j = 0; j < 8; ++j){
        float v = 16.f * xb[(kt*32 + lg*8 + j) * LL + tok];
        u16 hb = bf16_rn(v);
        float hf = __uint_as_float((u32)hb << 16);
        u16 lb = bf16_rn(v - hf);
        Bh[ct][kt][j] = (short)hb;
        Bl[ct][kt][j] = (short)lb;
      }
    }
  }

  int k1[4], k2[4];
  #pragma unroll
  for (int ct = 0; ct < 4; ++ct){ k1[ct] = 0x7fffffff; k2[ct] = 0x7fffffff; }

  // wave's lane-fixed sub-addresses within each 64-code tile (4 16-code tiles;
  // wave w owns sub-tile w): u32 offset w*1024 + l*4
  const u32* ehp = eh + w*1024 + l*4;
  const u32* elp = el + w*1024 + l*4;

  bf16x8 A0h[4], A0l[4], A1h[4], A1l[4];
  load_tile(ehp, elp, 0, A0h, A0l);
  f32x4 s2v0 = s2k4[w*4 + lg], s2v1;

  for (int it = 0; it < 128; it += 2){
    load_tile(ehp, elp, it+1, A1h, A1l);
    s2v1 = s2k4[(it+1)*16 + w*4 + lg];
    compute_tile(A0h, A0l, Bh, Bl, s2v0, it*64 + w*16 + lg*4, k1, k2);

    int it2 = (it+2 < 128) ? it+2 : 127;
    load_tile(ehp, elp, it2, A0h, A0l);
    s2v0 = s2k4[it2*16 + w*4 + lg];
    compute_tile(A1h, A1l, Bh, Bl, s2v1, (it+1)*64 + w*16 + lg*4, k1, k2);
  }

  #pragma unroll
  for (int ct = 0; ct < 4; ++ct){
    int sidx = (ct*16 + lr)*16 + w*4 + lg;   // state order == ascending j order
    kk1[sidx] = k1[ct];
    kk2[sidx] = k2[ct];
  }
  __syncthreads();
  if (t < 64){
    int K1 = 0x7fffffff, K2 = 0x7fffffff;
    #pragma unroll 4
    for (int s = 0; s < 16; ++s){
      int a = kk1[t*16 + s], b2 = kk2[t*16 + s];
      int mx = max(a, K1);  K2 = min(mx, K2);  K1 = min(a, K1);
      mx = max(b2, K1);     K2 = min(mx, K2);  K1 = min(b2, K1);
    }
    idx1o[n0 + t] = K1 & 8191;
    idx2o[n0 + t] = K2 & 8191;
  }
}

// ---------- exact fp32 re-rank + fit + prenorm stats + histogram ----------
__global__ __launch_bounds__(256) void fixup_kernel(const float* __restrict__ x,
    const float* __restrict__ e,
    const int* __restrict__ idx1, const int* __restrict__ idx2,
    int* __restrict__ idxf, int* __restrict__ cnt, float* __restrict__ accs)
{
  int n = blockIdx.x * 256 + threadIdx.x;
  int b = n >> 10, l = n & 1023;
  const float* xb = x + (size_t)b * (DD * LL) + l;
  int a = idx1[n], c = idx2[n];
  const float4* ea = (const float4*)&e[a * DD];
  const float4* ec = (const float4*)&e[c * DD];
  float s1 = 0.f, sx = 0.f, d1 = 0.f, d2 = 0.f, sa = 0.f, sc2 = 0.f;
  #pragma unroll 4
  for (int k4 = 0; k4 < 32; ++k4){
    float4 va = ea[k4], vc = ec[k4];
    float x0 = xb[(k4*4+0) * LL];
    float x1 = xb[(k4*4+1) * LL];
    float x2 = xb[(k4*4+2) * LL];
    float x3 = xb[(k4*4+3) * LL];
    s1 = fmaf(x0,x0, fmaf(x1,x1, fmaf(x2,x2, fmaf(x3,x3, s1))));
    sx += x0 + x1 + x2 + x3;
    d1 = fmaf(x0,va.x, fmaf(x1,va.y, fmaf(x2,va.z, fmaf(x3,va.w, d1))));
    d2 = fmaf(x0,vc.x, fmaf(x1,vc.y, fmaf(x2,vc.z, fmaf(x3,vc.w, d2))));
    sa = fmaf(va.x,va.x, fmaf(va.y,va.y, fmaf(va.z,va.z, fmaf(va.w,va.w, sa))));
    sc2= fmaf(vc.x,vc.x, fmaf(vc.y,vc.y, fmaf(vc.z,vc.z, fmaf(vc.w,vc.w, sc2))));
  }
  float da = s1 + sa  - 2.f * d1;
  float db = s1 + sc2 - 2.f * d2;
  int j; float dd;
  if (db < da || (db == da && c < a)) { j = c; dd = db; }
  else                                { j = a; dd = da; }
  idxf[n] = j;
  atomicAdd(&cnt[j], 1);
  dd = waveSum(dd); s1 = waveSum(s1); sx = waveSum(sx);
  if ((threadIdx.x & 63) == 0){
    atomicAdd(&accs[3], dd);
    atomicAdd(&accs[1], s1);
    atomicAdd(&accs[0], sx);
  }
}

// ---------- single-block prefix scan: cnt -> cursor(start), kelem ----------
__global__ __launch_bounds__(1024) void prefix_kernel(const int* __restrict__ cnt,
    int* __restrict__ cursor, float* __restrict__ kelem)
{
  __shared__ int sc[1024];
  int t = threadIdx.x;
  int c[8]; int s = 0;
  #pragma unroll
  for (int i = 0; i < 8; ++i){ c[i] = cnt[t*8 + i]; s += c[i]; }
  sc[t] = s;
  __syncthreads();
  for (int off = 1; off < 1024; off <<= 1){
    int v = sc[t];
    int u = (t >= off) ? sc[t - off] : 0;
    __syncthreads();
    sc[t] = v + u;
    __syncthreads();
  }
  int base = t ? sc[t-1] : 0;
  #pragma unroll
  for (int i = 0; i < 8; ++i){
    cursor[t*8 + i] = base;
    kelem[t*8 + i] = (float)c[i];
    base += c[i];
  }
}

// ---------- scatter token ids into code-sorted order ----------
__global__ __launch_bounds__(256) void scatter_kernel(const int* __restrict__ idxf,
    int* __restrict__ cursor, int* __restrict__ order)
{
  int n = blockIdx.x * 256 + threadIdx.x;
  int j = idxf[n];
  int p = atomicAdd(&cursor[j], 1);
  order[p] = n;
}

// ---------- transpose x[b][d][l] -> xT[token][d] (coalesced both sides) ----
__global__ __launch_bounds__(256) void transpose_kernel(const float* __restrict__ x,
    float* __restrict__ xT)
{
  __shared__ float tile[64][137];   // 137: odd dword stride, 2-way max
  int t = threadIdx.x;
  int b  = blockIdx.x >> 4;
  int l0 = (blockIdx.x & 15) << 6;
  const float* xb = x + (size_t)b * (DD * LL);
  #pragma unroll
  for (int rep = 0; rep < 32; ++rep){
    int idx = rep * 256 + t;
    int d = idx >> 6, ll = idx & 63;
    tile[ll][d] = xb[d * LL + l0 + ll];
  }
  __syncthreads();
  int n0 = (b << 10) + l0;
  #pragma unroll
  for (int rep = 0; rep < 8; ++rep){
    int idx = rep * 256 + t;
    int row = idx >> 5, c4 = idx & 31;
    float4 v;
    v.x = tile[row][c4*4+0]; v.y = tile[row][c4*4+1];
    v.z = tile[row][c4*4+2]; v.w = tile[row][c4*4+3];
    *(float4*)&xT[(size_t)(n0 + row) * DD + c4*4] = v;
  }
}

// ---------- atomic-free ksum from xT (contiguous 512B per member) ----------
__global__ __launch_bounds__(256) void ksum_xt_kernel(const float* __restrict__ xT,
    const int* __restrict__ order, const int* __restrict__ cnt,
    const int* __restrict__ cursor, float* __restrict__ ksum)
{
  int w = threadIdx.x >> 6, lane = threadIdx.x & 63;
  int j = blockIdx.x * 4 + w;
  int c = cnt[j];
  int st = cursor[j] - c;          // cursor is end after scatter
  float a0 = 0.f, a1 = 0.f;
  for (int k = 0; k < c; ++k){
    int n = order[st + k];
    const float* xr = xT + (size_t)n * DD;
    a0 += xr[lane];
    a1 += xr[64 + lane];
  }
  ksum[j * DD + lane]      = a0;
  ksum[j * DD + 64 + lane] = a1;
}

// ---------- fallback ksum reading x columns (if ws too small for xT) ------
__global__ __launch_bounds__(256) void ksum_kernel(const float* __restrict__ x,
    const int* __restrict__ order, const int* __restrict__ cnt,
    const int* __restrict__ cursor, float* __restrict__ ksum)
{
  int w = threadIdx.x >> 6, lane = threadIdx.x & 63;
  int j = blockIdx.x * 4 + w;
  int c = cnt[j];
  int st = cursor[j] - c;
  float a0 = 0.f, a1 = 0.f;
  for (int k = 0; k < c; ++k){
    int n = order[st + k];
    int b = n >> 10, l = n & 1023;
    const float* xb = x + (size_t)b * (DD * LL) + l;
    a0 += xb[lane * LL];
    a1 += xb[(lane + 64) * LL];
  }
  ksum[j * DD + lane]      = a0;
  ksum[j * DD + 64 + lane] = a1;
}

// ---------- gather quantized, STE out, commit loss ----------
__global__ __launch_bounds__(256) void out_kernel(const float* __restrict__ x,
   const float* __restrict__ e, const int* __restrict__ idxf,
   float* __restrict__ out, float* __restrict__ quant, float* __restrict__ accs)
{
  int gid = blockIdx.x * 256 + threadIdx.x;    // one float4 per thread
  int l4 = gid & 255;
  int d  = (gid >> 8) & 127;
  int b  = gid >> 15;
  int n0 = (b << 10) + l4 * 4;
  int4 jv = *(const int4*)&idxf[n0];
  float4 xv = *(const float4*)&x[(size_t)gid * 4];
  float4 q;
  q.x = e[jv.x * DD + d];
  q.y = e[jv.y * DD + d];
  q.z = e[jv.z * DD + d];
  q.w = e[jv.w * DD + d];
  float4 df = make_float4(q.x - xv.x, q.y - xv.y, q.z - xv.z, q.w - xv.w);
  float4 ov = make_float4(xv.x + df.x, xv.y + df.y, xv.z + df.z, xv.w + df.w);
  *(float4*)&out[(size_t)gid * 4]   = ov;
  *(float4*)&quant[(size_t)gid * 4] = q;
  float cc = df.x*df.x + df.y*df.y + df.z*df.z + df.w*df.w;
  cc = waveSum(cc);
  __shared__ float cs[4];
  if ((threadIdx.x & 63) == 0) cs[threadIdx.x >> 6] = cc;
  __syncthreads();
  if (threadIdx.x == 0) atomicAdd(&accs[2], cs[0]+cs[1]+cs[2]+cs[3]);
}

// ---------- entropy + scalar finalize ----------
__global__ __launch_bounds__(256) void final_kernel(const float* __restrict__ kelem,
    const float* __restrict__ accs, float* __restrict__ scal)
{
  int t = threadIdx.x;
  double es = 0.0;
  for (int i = t; i < NE; i += 256){
    float p = kelem[i] * (1.0f / NN);
    es += (double)(p * logf(p + 1e-8f));
  }
  es = waveSumD(es);
  __shared__ double er[4];
  if ((t & 63) == 0) er[t >> 6] = es;
  __syncthreads();
  if (t == 0){
    double ent = -(er[0]+er[1]+er[2]+er[3]);
    float sum = accs[0], sq = accs[1], commit = accs[2], fitsum = accs[3];
    double mu  = (double)sum / (double)XSZ;
    double var = (double)sq / (double)XSZ - mu * mu;
    if (var < 0) var = 0;
    scal[0] = (float)(0.25 * (double)commit / (double)XSZ);
    scal[1] = (float)((double)fitsum / (double)NN);
    scal[2] = (float)sqrt(var);
    scal[3] = (float)ent;
  }
}

extern "C" void kernel_launch(void* const* d_in, const int* in_sizes, int n_in,
                              void* d_out, int out_size, void* d_ws, size_t ws_size,
                              hipStream_t stream)
{
  const float* x = (const float*)d_in[0];
  const float* e = (const float*)d_in[1];
  float* out   = (float*)d_out;
  float* quant = out + OUT_OFF_Q;
  float* scal  = out + OUT_OFF_SCAL;
  float* ksum  = out + OUT_OFF_KSUM;
  float* kelem = out + OUT_OFF_KELEM;

  // ws: eh 2MB | el 2MB | s2k 32KB | idx1/idx2/idxf 128KB ea | cnt/cursor 32KB |
  //     order 128KB | accs | xT 16MB @ 5MB
  char* wsb = (char*)d_ws;
  u32*   eh     = (u32*)(wsb);
  u32*   el     = (u32*)(wsb + 2097152);
  float* s2k    = (float*)(wsb + 4194304);
  int*   idx1   = (int*)(wsb + 4227072);
  int*   idx2   = (int*)(wsb + 4358144);
  int*   idxf   = (int*)(wsb + 4489216);
  int*   cnt    = (int*)(wsb + 4620288);
  int*   cursor = (int*)(wsb + 4653056);
  int*   order  = (int*)(wsb + 4685824);
  float* accs   = (float*)(wsb + 4816896);
  float* xT     = (float*)(wsb + 5242880);
  bool useXT = ws_size >= (size_t)(5242880 + 16777216);

  hipMemsetAsync(accs, 0, 32, stream);
  hipMemsetAsync(cnt, 0, NE * 4, stream);

  prep_kernel   <<<NE / 4,     256, 0, stream>>>(e, eh, el, s2k);
  argmin_mfma   <<<NN / 64,    256, 0, stream>>>(x, eh, el, (const f32x4*)s2k,
                                                 idx1, idx2);
  fixup_kernel  <<<NN / 256,   256, 0, stream>>>(x, e, idx1, idx2, idxf, cnt, accs);
  prefix_kernel <<<1,         1024, 0, stream>>>(cnt, cursor, kelem);
  scatter_kernel<<<NN / 256,   256, 0, stream>>>(idxf, cursor, order);
  if (useXT){
    transpose_kernel<<<BB * 16, 256, 0, stream>>>(x, xT);
    ksum_xt_kernel  <<<NE / 4,  256, 0, stream>>>(xT, order, cnt, cursor, ksum);
  } else {
    ksum_kernel     <<<NE / 4,  256, 0, stream>>>(x, order, cnt, cursor, ksum);
  }
  out_kernel    <<<XSZ / 1024, 256, 0, stream>>>(x, e, idxf, out, quant, accs);
  final_kernel  <<<1,          256, 0, stream>>>(kelem, accs, scal);
}

// Round 6
// 386.380 us; speedup vs baseline: 5.4013x; 1.2061x over previous
//
#include <hip/hip_runtime.h>
#include <math.h>
#include <float.h>

#define BB 32
#define DD 128
#define LL 1024
#define NN 32768
#define NE 8192
#define XSZ 4194304
#define OUT_OFF_Q     4194304
#define OUT_OFF_SCAL  8388608
#define OUT_OFF_KSUM  8388612
#define OUT_OFF_KELEM 9437188

typedef unsigned int u32;
typedef unsigned short u16;
typedef int   i32x4 __attribute__((ext_vector_type(4)));
typedef float f32x4 __attribute__((ext_vector_type(4)));

__device__ inline float waveSum(float v){
  #pragma unroll
  for (int o = 32; o > 0; o >>= 1) v += __shfl_down(v, o, 64);
  return v;
}
__device__ inline double waveSumD(double v){
  #pragma unroll
  for (int o = 32; o > 0; o >>= 1) v += __shfl_down(v, o, 64);
  return v;
}

// ---------- prep: int8 hi/lo planes of round(4096*e), s2c = 65536+s2_int/65536
// Fragment-linear layout for mfma_i32_16x16x64_i8:
//  byte addr = (T16*2 + kt2)*1024 + ((k>>4)&3)*256 + (row&15)*16 + (k&15)
//  (lane l = (k>>4)*16 + row&15 reads 16B at chunk + l*16)
__global__ __launch_bounds__(256) void prep_kernel(const float* __restrict__ e,
    u16* __restrict__ eh8, u16* __restrict__ el8, float* __restrict__ s2c)
{
  int t = threadIdx.x;
  int row = blockIdx.x * 4 + (t >> 6);
  int kd  = t & 63;                       // k = 2kd, 2kd+1
  float2 ev = *reinterpret_cast<const float2*>(&e[row * DD + kd * 2]);
  int e0 = __float2int_rn(ev.x * 4096.f);
  int e1 = __float2int_rn(ev.y * 4096.f);
  e0 = min(max(e0, -32639), 32639);
  e1 = min(max(e1, -32639), 32639);
  double sq = (double)e0 * (double)e0 + (double)e1 * (double)e1;
  sq = waveSumD(sq);
  if (kd == 0) s2c[row] = (float)(65536.0 + sq * (1.0 / 65536.0));
  int h0 = (e0 + 128) >> 8, l0_ = e0 - (h0 << 8);
  int h1 = (e1 + 128) >> 8, l1_ = e1 - (h1 << 8);
  int k = kd * 2;
  int T16 = row >> 4, lr = row & 15;
  int kt2 = k >> 6, lg = (k >> 4) & 3, j = k & 15;
  int du16 = (((T16*2 + kt2) * 1024) + lg*256 + lr*16 + j) >> 1;
  eh8[du16] = (u16)((h0 & 255) | ((h1 & 255) << 8));
  el8[du16] = (u16)((l0_ & 255) | ((l1_ & 255) << 8));
}

// ---------- MFMA argmin: i8x3 split, direct L2 A-path, deferred keys ------
__device__ __forceinline__ void load_tileA(const u32* __restrict__ ph,
    const u32* __restrict__ pl, int Tw, i32x4 (&Ah)[2], i32x4 (&Al)[2])
{
  #pragma unroll
  for (int kt = 0; kt < 2; ++kt){
    Ah[kt] = *(const i32x4*)(ph + (size_t)(Tw*2 + kt) * 256);
    Al[kt] = *(const i32x4*)(pl + (size_t)(Tw*2 + kt) * 256);
  }
}

__device__ __forceinline__ void mfma_tile(const i32x4 (&Ah)[2], const i32x4 (&Al)[2],
    const i32x4 (&Bh)[4][2], const i32x4 (&Bl)[4][2],
    i32x4 (&t1)[4], i32x4 (&t2)[4])
{
  const i32x4 ZV = {0,0,0,0};
  #pragma unroll
  for (int ct = 0; ct < 4; ++ct){ t1[ct] = ZV; t2[ct] = ZV; }
  __builtin_amdgcn_s_setprio(1);
  #pragma unroll
  for (int kt = 0; kt < 2; ++kt){
    #pragma unroll
    for (int ct = 0; ct < 4; ++ct)
      t1[ct] = __builtin_amdgcn_mfma_i32_16x16x64_i8(Ah[kt], Bh[ct][kt], t1[ct], 0,0,0);
    #pragma unroll
    for (int ct = 0; ct < 4; ++ct)
      t2[ct] = __builtin_amdgcn_mfma_i32_16x16x64_i8(Al[kt], Bh[ct][kt], t2[ct], 0,0,0);
    #pragma unroll
    for (int ct = 0; ct < 4; ++ct)
      t2[ct] = __builtin_amdgcn_mfma_i32_16x16x64_i8(Ah[kt], Bl[ct][kt], t2[ct], 0,0,0);
  }
  __builtin_amdgcn_s_setprio(0);
}

// key = (int)(s2c - 2*T1 - T2/128) << 13 | j  (65536+256*dist scale)
__device__ __forceinline__ void keys_update(const i32x4 (&t1)[4], const i32x4 (&t2)[4],
    f32x4 s2v, int jb, int (&k1)[4], int (&k2)[4])
{
  #pragma unroll
  for (int ct = 0; ct < 4; ++ct){
    #pragma unroll
    for (int r = 0; r < 4; ++r){
      float vf = fmaf((float)t1[ct][r], -2.f, s2v[r]);
      vf = fmaf((float)t2[ct][r], -0.0078125f, vf);
      int key = (((int)vf) << 13) + (jb + r);
      int mx = max(key, k1[ct]);
      k2[ct] = min(mx, k2[ct]);
      k1[ct] = min(key, k1[ct]);
    }
  }
}

__global__ __launch_bounds__(256, 2) void argmin_mfma(
    const float* __restrict__ x,
    const u32* __restrict__ eh8, const u32* __restrict__ el8,
    const f32x4* __restrict__ s2c4,
    int* __restrict__ idx1o, int* __restrict__ idx2o)
{
  __shared__ int kk1[1024];
  __shared__ int kk2[1024];

  int t  = threadIdx.x;
  int w  = t >> 6;
  int l  = t & 63;
  int lr = l & 15;
  int lg = l >> 4;

  int blk  = blockIdx.x;
  int half = blk >> 9;              // code half: [0,4096) or [4096,8192)
  int tb   = blk & 511;
  int hb64 = half * 64;             // first 64-code tile of this half

  int n0 = tb * 64;
  int b  = n0 >> 10;
  int l0 = n0 & 1023;
  const float* xb = x + (size_t)b * (DD * LL);

  // B fragments: 64 tokens, i8 hi/lo planes of round(4096*x)
  i32x4 Bh[4][2], Bl[4][2];
  #pragma unroll
  for (int ct = 0; ct < 4; ++ct){
    int tok = l0 + ct*16 + lr;
    #pragma unroll
    for (int kt = 0; kt < 2; ++kt){
      #pragma unroll
      for (int dw = 0; dw < 4; ++dw){
        u32 hw = 0, lw = 0;
        #pragma unroll
        for (int bb = 0; bb < 4; ++bb){
          int k = kt*64 + lg*16 + dw*4 + bb;
          int xi = __float2int_rn(xb[(size_t)k * LL + tok] * 4096.f);
          xi = min(max(xi, -32639), 32639);
          int h  = (xi + 128) >> 8;
          int lo = xi - (h << 8);
          hw |= ((u32)h  & 255u) << (8*bb);
          lw |= ((u32)lo & 255u) << (8*bb);
        }
        Bh[ct][kt][dw] = (int)hw;
        Bl[ct][kt][dw] = (int)lw;
      }
    }
  }

  int k1[4], k2[4];
  #pragma unroll
  for (int ct = 0; ct < 4; ++ct){ k1[ct] = 0x7fffffff; k2[ct] = 0x7fffffff; }

  const u32* ehp = eh8 + (size_t)l * 4;
  const u32* elp = el8 + (size_t)l * 4;

  i32x4 A0h[2], A0l[2], A1h[2], A1l[2];
  i32x4 c1a[4], c2a[4], c1b[4], c2b[4], p1[4], p2[4];
  const i32x4 ZV = {0,0,0,0};
  #pragma unroll
  for (int ct = 0; ct < 4; ++ct){ p1[ct] = ZV; p2[ct] = ZV; }
  f32x4 s2vP = {240000.f, 240000.f, 240000.f, 240000.f};   // sentinel prev
  int jbP = 0;

  load_tileA(ehp, elp, (hb64 + 0)*4 + w, A0h, A0l);
  f32x4 s2v0 = s2c4[(hb64 + 0)*16 + w*4 + lg];
  load_tileA(ehp, elp, (hb64 + 1)*4 + w, A1h, A1l);
  f32x4 s2v1 = s2c4[(hb64 + 1)*16 + w*4 + lg];

  for (int it = 0; it < 64; it += 2){
    mfma_tile(A0h, A0l, Bh, Bl, c1a, c2a);
    keys_update(p1, p2, s2vP, jbP, k1, k2);          // prev tile's keys (VALU shadow)
    #pragma unroll
    for (int ct = 0; ct < 4; ++ct){ p1[ct] = c1a[ct]; p2[ct] = c2a[ct]; }
    s2vP = s2v0; jbP = (hb64 + it)*64 + w*16 + lg*4;
    int Tn = (it+2 < 64) ? it+2 : 63;
    load_tileA(ehp, elp, (hb64 + Tn)*4 + w, A0h, A0l);
    s2v0 = s2c4[(hb64 + Tn)*16 + w*4 + lg];

    mfma_tile(A1h, A1l, Bh, Bl, c1b, c2b);
    keys_update(p1, p2, s2vP, jbP, k1, k2);
    #pragma unroll
    for (int ct = 0; ct < 4; ++ct){ p1[ct] = c1b[ct]; p2[ct] = c2b[ct]; }
    s2vP = s2v1; jbP = (hb64 + it + 1)*64 + w*16 + lg*4;
    int Tn2 = (it+3 < 64) ? it+3 : 63;
    load_tileA(ehp, elp, (hb64 + Tn2)*4 + w, A1h, A1l);
    s2v1 = s2c4[(hb64 + Tn2)*16 + w*4 + lg];
  }
  keys_update(p1, p2, s2vP, jbP, k1, k2);            // epilogue: last tile

  #pragma unroll
  for (int ct = 0; ct < 4; ++ct){
    int sidx = (ct*16 + lr)*16 + w*4 + lg;
    kk1[sidx] = k1[ct];
    kk2[sidx] = k2[ct];
  }
  __syncthreads();
  if (t < 64){
    int K1 = 0x7fffffff, K2 = 0x7fffffff;
    #pragma unroll 4
    for (int s = 0; s < 16; ++s){
      int a = kk1[t*16 + s], b2 = kk2[t*16 + s];
      int mx = max(a, K1);  K2 = min(mx, K2);  K1 = min(a, K1);
      mx = max(b2, K1);     K2 = min(mx, K2);  K1 = min(b2, K1);
    }
    idx1o[half*NN + n0 + t] = K1 & 8191;
    idx2o[half*NN + n0 + t] = K2 & 8191;
  }
}

// ---------- exact fp32 re-rank of 4 candidates + fused out/quant/commit ----
__global__ __launch_bounds__(128) void fixup_kernel(const float* __restrict__ x,
    const float* __restrict__ e,
    const int* __restrict__ idx1, const int* __restrict__ idx2,
    int* __restrict__ idxf, int* __restrict__ cnt, float* __restrict__ accs,
    float* __restrict__ out, float* __restrict__ quant)
{
  int n = blockIdx.x * 128 + threadIdx.x;
  int b = n >> 10, l = n & 1023;
  size_t xoff = (size_t)b * (DD * LL) + l;
  const float* xb = x + xoff;
  int js[4];
  js[0] = idx1[n];      js[1] = idx2[n];
  js[2] = idx1[NN + n]; js[3] = idx2[NN + n];
  const float4* er[4];
  #pragma unroll
  for (int i = 0; i < 4; ++i) er[i] = (const float4*)&e[js[i] * DD];

  float s1 = 0.f, sx = 0.f;
  float dt[4] = {0.f,0.f,0.f,0.f}, sq[4] = {0.f,0.f,0.f,0.f};
  #pragma unroll 2
  for (int k4 = 0; k4 < 32; ++k4){
    float xv[4];
    #pragma unroll
    for (int r = 0; r < 4; ++r) xv[r] = xb[(size_t)(k4*4 + r) * LL];
    s1 = fmaf(xv[0],xv[0], fmaf(xv[1],xv[1], fmaf(xv[2],xv[2], fmaf(xv[3],xv[3], s1))));
    sx += xv[0] + xv[1] + xv[2] + xv[3];
    #pragma unroll
    for (int i = 0; i < 4; ++i){
      float4 v = er[i][k4];
      dt[i] = fmaf(xv[0],v.x, fmaf(xv[1],v.y, fmaf(xv[2],v.z, fmaf(xv[3],v.w, dt[i]))));
      sq[i] = fmaf(v.x,v.x, fmaf(v.y,v.y, fmaf(v.z,v.z, fmaf(v.w,v.w, sq[i]))));
    }
  }
  int jw = js[0];
  float dw = s1 + sq[0] - 2.f * dt[0];
  #pragma unroll
  for (int i = 1; i < 4; ++i){
    float di = s1 + sq[i] - 2.f * dt[i];
    if (di < dw || (di == dw && js[i] < jw)) { dw = di; jw = js[i]; }
  }
  idxf[n] = jw;
  atomicAdd(&cnt[jw], 1);

  // pass 2: winner row -> out/quant, commit loss
  const float4* ew = (const float4*)&e[jw * DD];
  float cm = 0.f;
  #pragma unroll 2
  for (int k4 = 0; k4 < 32; ++k4){
    float4 q = ew[k4];
    #pragma unroll
    for (int r = 0; r < 4; ++r){
      size_t o = xoff + (size_t)(k4*4 + r) * LL;
      float xv = x[o];
      float qr = (r == 0) ? q.x : (r == 1) ? q.y : (r == 2) ? q.z : q.w;
      float df = qr - xv;
      out[o]   = xv + df;
      quant[o] = qr;
      cm = fmaf(df, df, cm);
    }
  }
  dw = waveSum(dw); s1 = waveSum(s1); sx = waveSum(sx); cm = waveSum(cm);
  if ((threadIdx.x & 63) == 0){
    atomicAdd(&accs[3], dw);
    atomicAdd(&accs[1], s1);
    atomicAdd(&accs[0], sx);
    atomicAdd(&accs[2], cm);
  }
}

// ---------- single-block prefix scan: cnt -> cursor(start), kelem ----------
__global__ __launch_bounds__(1024) void prefix_kernel(const int* __restrict__ cnt,
    int* __restrict__ cursor, float* __restrict__ kelem)
{
  __shared__ int sc[1024];
  int t = threadIdx.x;
  int c[8]; int s = 0;
  #pragma unroll
  for (int i = 0; i < 8; ++i){ c[i] = cnt[t*8 + i]; s += c[i]; }
  sc[t] = s;
  __syncthreads();
  for (int off = 1; off < 1024; off <<= 1){
    int v = sc[t];
    int u = (t >= off) ? sc[t - off] : 0;
    __syncthreads();
    sc[t] = v + u;
    __syncthreads();
  }
  int base = t ? sc[t-1] : 0;
  #pragma unroll
  for (int i = 0; i < 8; ++i){
    cursor[t*8 + i] = base;
    kelem[t*8 + i] = (float)c[i];
    base += c[i];
  }
}

// ---------- scatter token ids into code-sorted order ----------
__global__ __launch_bounds__(256) void scatter_kernel(const int* __restrict__ idxf,
    int* __restrict__ cursor, int* __restrict__ order)
{
  int n = blockIdx.x * 256 + threadIdx.x;
  int j = idxf[n];
  int p = atomicAdd(&cursor[j], 1);
  order[p] = n;
}

// ---------- transpose x[b][d][l] -> xT[token][d] ----------
__global__ __launch_bounds__(256) void transpose_kernel(const float* __restrict__ x,
    float* __restrict__ xT)
{
  __shared__ float tile[64][137];
  int t = threadIdx.x;
  int b  = blockIdx.x >> 4;
  int l0 = (blockIdx.x & 15) << 6;
  const float* xb = x + (size_t)b * (DD * LL);
  #pragma unroll
  for (int rep = 0; rep < 32; ++rep){
    int idx = rep * 256 + t;
    int d = idx >> 6, ll = idx & 63;
    tile[ll][d] = xb[d * LL + l0 + ll];
  }
  __syncthreads();
  int n0 = (b << 10) + l0;
  #pragma unroll
  for (int rep = 0; rep < 8; ++rep){
    int idx = rep * 256 + t;
    int row = idx >> 5, c4 = idx & 31;
    float4 v;
    v.x = tile[row][c4*4+0]; v.y = tile[row][c4*4+1];
    v.z = tile[row][c4*4+2]; v.w = tile[row][c4*4+3];
    *(float4*)&xT[(size_t)(n0 + row) * DD + c4*4] = v;
  }
}

// ---------- atomic-free ksum from xT ----------
__global__ __launch_bounds__(256) void ksum_xt_kernel(const float* __restrict__ xT,
    const int* __restrict__ order, const int* __restrict__ cnt,
    const int* __restrict__ cursor, float* __restrict__ ksum)
{
  int w = threadIdx.x >> 6, lane = threadIdx.x & 63;
  int j = blockIdx.x * 4 + w;
  int c = cnt[j];
  int st = cursor[j] - c;
  float a0 = 0.f, a1 = 0.f;
  for (int k = 0; k < c; ++k){
    int n = order[st + k];
    const float* xr = xT + (size_t)n * DD;
    a0 += xr[lane];
    a1 += xr[64 + lane];
  }
  ksum[j * DD + lane]      = a0;
  ksum[j * DD + 64 + lane] = a1;
}

// ---------- fallback ksum reading x columns ----------
__global__ __launch_bounds__(256) void ksum_kernel(const float* __restrict__ x,
    const int* __restrict__ order, const int* __restrict__ cnt,
    const int* __restrict__ cursor, float* __restrict__ ksum)
{
  int w = threadIdx.x >> 6, lane = threadIdx.x & 63;
  int j = blockIdx.x * 4 + w;
  int c = cnt[j];
  int st = cursor[j] - c;
  float a0 = 0.f, a1 = 0.f;
  for (int k = 0; k < c; ++k){
    int n = order[st + k];
    int b = n >> 10, l = n & 1023;
    const float* xb = x + (size_t)b * (DD * LL) + l;
    a0 += xb[lane * LL];
    a1 += xb[(lane + 64) * LL];
  }
  ksum[j * DD + lane]      = a0;
  ksum[j * DD + 64 + lane] = a1;
}

// ---------- entropy + scalar finalize ----------
__global__ __launch_bounds__(256) void final_kernel(const float* __restrict__ kelem,
    const float* __restrict__ accs, float* __restrict__ scal)
{
  int t = threadIdx.x;
  double es = 0.0;
  for (int i = t; i < NE; i += 256){
    float p = kelem[i] * (1.0f / NN);
    es += (double)(p * logf(p + 1e-8f));
  }
  es = waveSumD(es);
  __shared__ double er[4];
  if ((t & 63) == 0) er[t >> 6] = es;
  __syncthreads();
  if (t == 0){
    double ent = -(er[0]+er[1]+er[2]+er[3]);
    float sum = accs[0], sq = accs[1], commit = accs[2], fitsum = accs[3];
    double mu  = (double)sum / (double)XSZ;
    double var = (double)sq / (double)XSZ - mu * mu;
    if (var < 0) var = 0;
    scal[0] = (float)(0.25 * (double)commit / (double)XSZ);
    scal[1] = (float)((double)fitsum / (double)NN);
    scal[2] = (float)sqrt(var);
    scal[3] = (float)ent;
  }
}

extern "C" void kernel_launch(void* const* d_in, const int* in_sizes, int n_in,
                              void* d_out, int out_size, void* d_ws, size_t ws_size,
                              hipStream_t stream)
{
  const float* x = (const float*)d_in[0];
  const float* e = (const float*)d_in[1];
  float* out   = (float*)d_out;
  float* quant = out + OUT_OFF_Q;
  float* scal  = out + OUT_OFF_SCAL;
  float* ksum  = out + OUT_OFF_KSUM;
  float* kelem = out + OUT_OFF_KELEM;

  // ws: eh8 1MB | el8 1MB | s2c 32KB | idx1 256KB | idx2 256KB | idxf 128KB |
  //     cnt 32KB | cursor 32KB | order 128KB | accs | xT 16MB @ 4MB
  char* wsb = (char*)d_ws;
  u16*   eh8    = (u16*)(wsb);
  u16*   el8    = (u16*)(wsb + 1048576);
  float* s2c    = (float*)(wsb + 2097152);
  int*   idx1   = (int*)(wsb + 2129920);
  int*   idx2   = (int*)(wsb + 2392064);
  int*   idxf   = (int*)(wsb + 2654208);
  int*   cnt    = (int*)(wsb + 2785280);
  int*   cursor = (int*)(wsb + 2818048);
  int*   order  = (int*)(wsb + 2850816);
  float* accs   = (float*)(wsb + 2981888);
  float* xT     = (float*)(wsb + 4194304);
  bool useXT = ws_size >= (size_t)(4194304 + 16777216);

  hipMemsetAsync(accs, 0, 32, stream);
  hipMemsetAsync(cnt, 0, NE * 4, stream);

  prep_kernel   <<<NE / 4,     256, 0, stream>>>(e, eh8, el8, s2c);
  argmin_mfma   <<<1024,       256, 0, stream>>>(x, (const u32*)eh8, (const u32*)el8,
                                                 (const f32x4*)s2c, idx1, idx2);
  fixup_kernel  <<<NN / 128,   128, 0, stream>>>(x, e, idx1, idx2, idxf, cnt, accs,
                                                 out, quant);
  prefix_kernel <<<1,         1024, 0, stream>>>(cnt, cursor, kelem);
  scatter_kernel<<<NN / 256,   256, 0, stream>>>(idxf, cursor, order);
  if (useXT){
    transpose_kernel<<<BB * 16, 256, 0, stream>>>(x, xT);
    ksum_xt_kernel  <<<NE / 4,  256, 0, stream>>>(xT, order, cnt, cursor, ksum);
  } else {
    ksum_kernel     <<<NE / 4,  256, 0, stream>>>(x, order, cnt, cursor, ksum);
  }
  final_kernel  <<<1,          256, 0, stream>>>(kelem, accs, scal);
}

// Round 7
// 236.222 us; speedup vs baseline: 8.8347x; 1.6357x over previous
//
#include <hip/hip_runtime.h>
#include <math.h>
#include <float.h>

#define BB 32
#define DD 128
#define LL 1024
#define NN 32768
#define NE 8192
#define XSZ 4194304
#define OUT_OFF_Q     4194304
#define OUT_OFF_SCAL  8388608
#define OUT_OFF_KSUM  8388612
#define OUT_OFF_KELEM 9437188

typedef unsigned int u32;
typedef unsigned short u16;
typedef int   i32x4 __attribute__((ext_vector_type(4)));
typedef float f32x4 __attribute__((ext_vector_type(4)));

__device__ inline float waveSum(float v){
  #pragma unroll
  for (int o = 32; o > 0; o >>= 1) v += __shfl_down(v, o, 64);
  return v;
}
__device__ inline double waveSumD(double v){
  #pragma unroll
  for (int o = 32; o > 0; o >>= 1) v += __shfl_down(v, o, 64);
  return v;
}

// ---------- prep: int8 hi/lo planes of round(4096*e), s2c = 65536+s2_int/65536
// Fragment-linear layout for mfma_i32_16x16x64_i8:
//  byte addr = (T16*2 + kt2)*1024 + ((k>>4)&3)*256 + (row&15)*16 + (k&15)
__global__ __launch_bounds__(256) void prep_kernel(const float* __restrict__ e,
    u16* __restrict__ eh8, u16* __restrict__ el8, float* __restrict__ s2c)
{
  int t = threadIdx.x;
  int row = blockIdx.x * 4 + (t >> 6);
  int kd  = t & 63;                       // k = 2kd, 2kd+1
  float2 ev = *reinterpret_cast<const float2*>(&e[row * DD + kd * 2]);
  int e0 = __float2int_rn(ev.x * 4096.f);
  int e1 = __float2int_rn(ev.y * 4096.f);
  e0 = min(max(e0, -32639), 32639);
  e1 = min(max(e1, -32639), 32639);
  double sq = (double)e0 * (double)e0 + (double)e1 * (double)e1;
  sq = waveSumD(sq);
  if (kd == 0) s2c[row] = (float)(65536.0 + sq * (1.0 / 65536.0));
  int h0 = (e0 + 128) >> 8, l0_ = e0 - (h0 << 8);
  int h1 = (e1 + 128) >> 8, l1_ = e1 - (h1 << 8);
  int k = kd * 2;
  int T16 = row >> 4, lr = row & 15;
  int kt2 = k >> 6, lg = (k >> 4) & 3, j = k & 15;
  int du16 = (((T16*2 + kt2) * 1024) + lg*256 + lr*16 + j) >> 1;
  eh8[du16] = (u16)((h0 & 255) | ((h1 & 255) << 8));
  el8[du16] = (u16)((l0_ & 255) | ((l1_ & 255) << 8));
}

// ---------- MFMA argmin: i8x3 split, direct L2 A-path, deferred keys ------
__device__ __forceinline__ void load_tileA(const u32* __restrict__ ph,
    const u32* __restrict__ pl, int Tw, i32x4 (&Ah)[2], i32x4 (&Al)[2])
{
  #pragma unroll
  for (int kt = 0; kt < 2; ++kt){
    Ah[kt] = *(const i32x4*)(ph + (size_t)(Tw*2 + kt) * 256);
    Al[kt] = *(const i32x4*)(pl + (size_t)(Tw*2 + kt) * 256);
  }
}

__device__ __forceinline__ void mfma_tile(const i32x4 (&Ah)[2], const i32x4 (&Al)[2],
    const i32x4 (&Bh)[4][2], const i32x4 (&Bl)[4][2],
    i32x4 (&t1)[4], i32x4 (&t2)[4])
{
  const i32x4 ZV = {0,0,0,0};
  #pragma unroll
  for (int ct = 0; ct < 4; ++ct){ t1[ct] = ZV; t2[ct] = ZV; }
  __builtin_amdgcn_s_setprio(1);
  #pragma unroll
  for (int kt = 0; kt < 2; ++kt){
    #pragma unroll
    for (int ct = 0; ct < 4; ++ct)
      t1[ct] = __builtin_amdgcn_mfma_i32_16x16x64_i8(Ah[kt], Bh[ct][kt], t1[ct], 0,0,0);
    #pragma unroll
    for (int ct = 0; ct < 4; ++ct)
      t2[ct] = __builtin_amdgcn_mfma_i32_16x16x64_i8(Al[kt], Bh[ct][kt], t2[ct], 0,0,0);
    #pragma unroll
    for (int ct = 0; ct < 4; ++ct)
      t2[ct] = __builtin_amdgcn_mfma_i32_16x16x64_i8(Ah[kt], Bl[ct][kt], t2[ct], 0,0,0);
  }
  __builtin_amdgcn_s_setprio(0);
}

// key = (int)(s2c - 2*T1 - T2/128) << 13 | j  (65536+256*dist scale)
__device__ __forceinline__ void keys_update(const i32x4 (&t1)[4], const i32x4 (&t2)[4],
    f32x4 s2v, int jb, int (&k1)[4], int (&k2)[4])
{
  #pragma unroll
  for (int ct = 0; ct < 4; ++ct){
    #pragma unroll
    for (int r = 0; r < 4; ++r){
      float vf = fmaf((float)t1[ct][r], -2.f, s2v[r]);
      vf = fmaf((float)t2[ct][r], -0.0078125f, vf);
      int key = (((int)vf) << 13) + (jb + r);
      int mx = max(key, k1[ct]);
      k2[ct] = min(mx, k2[ct]);
      k1[ct] = min(key, k1[ct]);
    }
  }
}

__global__ __launch_bounds__(256, 2) void argmin_mfma(
    const float* __restrict__ x,
    const u32* __restrict__ eh8, const u32* __restrict__ el8,
    const f32x4* __restrict__ s2c4,
    int* __restrict__ idx1o, int* __restrict__ idx2o)
{
  __shared__ int kk1[1024];
  __shared__ int kk2[1024];

  int t  = threadIdx.x;
  int w  = t >> 6;
  int l  = t & 63;
  int lr = l & 15;
  int lg = l >> 4;

  int blk  = blockIdx.x;
  int half = blk >> 9;              // code half: [0,4096) or [4096,8192)
  int tb   = blk & 511;
  int hb64 = half * 64;             // first 64-code tile of this half

  int n0 = tb * 64;
  int b  = n0 >> 10;
  int l0 = n0 & 1023;
  const float* xb = x + (size_t)b * (DD * LL);

  // B fragments: 64 tokens, i8 hi/lo planes of round(4096*x)
  i32x4 Bh[4][2], Bl[4][2];
  #pragma unroll
  for (int ct = 0; ct < 4; ++ct){
    int tok = l0 + ct*16 + lr;
    #pragma unroll
    for (int kt = 0; kt < 2; ++kt){
      #pragma unroll
      for (int dw = 0; dw < 4; ++dw){
        u32 hw = 0, lw = 0;
        #pragma unroll
        for (int bb = 0; bb < 4; ++bb){
          int k = kt*64 + lg*16 + dw*4 + bb;
          int xi = __float2int_rn(xb[(size_t)k * LL + tok] * 4096.f);
          xi = min(max(xi, -32639), 32639);
          int h  = (xi + 128) >> 8;
          int lo = xi - (h << 8);
          hw |= ((u32)h  & 255u) << (8*bb);
          lw |= ((u32)lo & 255u) << (8*bb);
        }
        Bh[ct][kt][dw] = (int)hw;
        Bl[ct][kt][dw] = (int)lw;
      }
    }
  }

  int k1[4], k2[4];
  #pragma unroll
  for (int ct = 0; ct < 4; ++ct){ k1[ct] = 0x7fffffff; k2[ct] = 0x7fffffff; }

  const u32* ehp = eh8 + (size_t)l * 4;
  const u32* elp = el8 + (size_t)l * 4;

  i32x4 A0h[2], A0l[2], A1h[2], A1l[2];
  i32x4 c1a[4], c2a[4], c1b[4], c2b[4], p1[4], p2[4];
  const i32x4 ZV = {0,0,0,0};
  #pragma unroll
  for (int ct = 0; ct < 4; ++ct){ p1[ct] = ZV; p2[ct] = ZV; }
  f32x4 s2vP = {240000.f, 240000.f, 240000.f, 240000.f};   // sentinel prev
  int jbP = 0;

  load_tileA(ehp, elp, (hb64 + 0)*4 + w, A0h, A0l);
  f32x4 s2v0 = s2c4[(hb64 + 0)*16 + w*4 + lg];
  load_tileA(ehp, elp, (hb64 + 1)*4 + w, A1h, A1l);
  f32x4 s2v1 = s2c4[(hb64 + 1)*16 + w*4 + lg];

  for (int it = 0; it < 64; it += 2){
    mfma_tile(A0h, A0l, Bh, Bl, c1a, c2a);
    keys_update(p1, p2, s2vP, jbP, k1, k2);          // prev tile's keys (VALU shadow)
    #pragma unroll
    for (int ct = 0; ct < 4; ++ct){ p1[ct] = c1a[ct]; p2[ct] = c2a[ct]; }
    s2vP = s2v0; jbP = (hb64 + it)*64 + w*16 + lg*4;
    int Tn = (it+2 < 64) ? it+2 : 63;
    load_tileA(ehp, elp, (hb64 + Tn)*4 + w, A0h, A0l);
    s2v0 = s2c4[(hb64 + Tn)*16 + w*4 + lg];

    mfma_tile(A1h, A1l, Bh, Bl, c1b, c2b);
    keys_update(p1, p2, s2vP, jbP, k1, k2);
    #pragma unroll
    for (int ct = 0; ct < 4; ++ct){ p1[ct] = c1b[ct]; p2[ct] = c2b[ct]; }
    s2vP = s2v1; jbP = (hb64 + it + 1)*64 + w*16 + lg*4;
    int Tn2 = (it+3 < 64) ? it+3 : 63;
    load_tileA(ehp, elp, (hb64 + Tn2)*4 + w, A1h, A1l);
    s2v1 = s2c4[(hb64 + Tn2)*16 + w*4 + lg];
  }
  keys_update(p1, p2, s2vP, jbP, k1, k2);            // epilogue: last tile

  #pragma unroll
  for (int ct = 0; ct < 4; ++ct){
    int sidx = (ct*16 + lr)*16 + w*4 + lg;
    kk1[sidx] = k1[ct];
    kk2[sidx] = k2[ct];
  }
  __syncthreads();
  if (t < 64){
    int K1 = 0x7fffffff, K2 = 0x7fffffff;
    #pragma unroll 4
    for (int s = 0; s < 16; ++s){
      int a = kk1[t*16 + s], b2 = kk2[t*16 + s];
      int mx = max(a, K1);  K2 = min(mx, K2);  K1 = min(a, K1);
      mx = max(b2, K1);     K2 = min(mx, K2);  K1 = min(b2, K1);
    }
    idx1o[half*NN + n0 + t] = K1 & 8191;
    idx2o[half*NN + n0 + t] = K2 & 8191;
  }
}

// ---------- exact fp32 re-rank of 4 candidates + fused out/quant/commit ----
__global__ __launch_bounds__(128) void fixup_kernel(const float* __restrict__ x,
    const float* __restrict__ e,
    const int* __restrict__ idx1, const int* __restrict__ idx2,
    int* __restrict__ idxf, int* __restrict__ cnt, float* __restrict__ accs,
    float* __restrict__ out, float* __restrict__ quant)
{
  int n = blockIdx.x * 128 + threadIdx.x;
  int b = n >> 10, l = n & 1023;
  size_t xoff = (size_t)b * (DD * LL) + l;
  const float* xb = x + xoff;
  int js[4];
  js[0] = idx1[n];      js[1] = idx2[n];
  js[2] = idx1[NN + n]; js[3] = idx2[NN + n];
  const float4* er[4];
  #pragma unroll
  for (int i = 0; i < 4; ++i) er[i] = (const float4*)&e[js[i] * DD];

  float s1 = 0.f, sx = 0.f;
  float dt[4] = {0.f,0.f,0.f,0.f}, sq[4] = {0.f,0.f,0.f,0.f};
  #pragma unroll 2
  for (int k4 = 0; k4 < 32; ++k4){
    float xv[4];
    #pragma unroll
    for (int r = 0; r < 4; ++r) xv[r] = xb[(size_t)(k4*4 + r) * LL];
    s1 = fmaf(xv[0],xv[0], fmaf(xv[1],xv[1], fmaf(xv[2],xv[2], fmaf(xv[3],xv[3], s1))));
    sx += xv[0] + xv[1] + xv[2] + xv[3];
    #pragma unroll
    for (int i = 0; i < 4; ++i){
      float4 v = er[i][k4];
      dt[i] = fmaf(xv[0],v.x, fmaf(xv[1],v.y, fmaf(xv[2],v.z, fmaf(xv[3],v.w, dt[i]))));
      sq[i] = fmaf(v.x,v.x, fmaf(v.y,v.y, fmaf(v.z,v.z, fmaf(v.w,v.w, sq[i]))));
    }
  }
  int jw = js[0];
  float dw = s1 + sq[0] - 2.f * dt[0];
  #pragma unroll
  for (int i = 1; i < 4; ++i){
    float di = s1 + sq[i] - 2.f * dt[i];
    if (di < dw || (di == dw && js[i] < jw)) { dw = di; jw = js[i]; }
  }
  idxf[n] = jw;
  atomicAdd(&cnt[jw], 1);

  // pass 2: winner row -> out/quant, commit loss
  const float4* ew = (const float4*)&e[jw * DD];
  float cm = 0.f;
  #pragma unroll 2
  for (int k4 = 0; k4 < 32; ++k4){
    float4 q = ew[k4];
    #pragma unroll
    for (int r = 0; r < 4; ++r){
      size_t o = xoff + (size_t)(k4*4 + r) * LL;
      float xv = x[o];
      float qr = (r == 0) ? q.x : (r == 1) ? q.y : (r == 2) ? q.z : q.w;
      float df = qr - xv;
      out[o]   = xv + df;
      quant[o] = qr;
      cm = fmaf(df, df, cm);
    }
  }
  dw = waveSum(dw); s1 = waveSum(s1); sx = waveSum(sx); cm = waveSum(cm);
  if ((threadIdx.x & 63) == 0){
    atomicAdd(&accs[3], dw);
    atomicAdd(&accs[1], s1);
    atomicAdd(&accs[0], sx);
    atomicAdd(&accs[2], cm);
  }
}

// ---------- single-block prefix scan: cnt -> cursor(start), kelem ----------
__global__ __launch_bounds__(1024) void prefix_kernel(const int* __restrict__ cnt,
    int* __restrict__ cursor, float* __restrict__ kelem)
{
  __shared__ int sc[1024];
  int t = threadIdx.x;
  int c[8]; int s = 0;
  #pragma unroll
  for (int i = 0; i < 8; ++i){ c[i] = cnt[t*8 + i]; s += c[i]; }
  sc[t] = s;
  __syncthreads();
  for (int off = 1; off < 1024; off <<= 1){
    int v = sc[t];
    int u = (t >= off) ? sc[t - off] : 0;
    __syncthreads();
    sc[t] = v + u;
    __syncthreads();
  }
  int base = t ? sc[t-1] : 0;
  #pragma unroll
  for (int i = 0; i < 8; ++i){
    cursor[t*8 + i] = base;
    kelem[t*8 + i] = (float)c[i];
    base += c[i];
  }
}

// ---------- scatter token ids into code-sorted order (+ sorted code ids) ----
__global__ __launch_bounds__(256) void scatter_kernel(const int* __restrict__ idxf,
    int* __restrict__ cursor, int* __restrict__ order, int* __restrict__ jsorted)
{
  int n = blockIdx.x * 256 + threadIdx.x;
  int j = idxf[n];
  int p = atomicAdd(&cursor[j], 1);
  order[p] = n;
  jsorted[p] = j;
}

// ---------- transpose x[b][d][l] -> xT[token][d] ----------
__global__ __launch_bounds__(256) void transpose_kernel(const float* __restrict__ x,
    float* __restrict__ xT)
{
  __shared__ float tile[64][137];
  int t = threadIdx.x;
  int b  = blockIdx.x >> 4;
  int l0 = (blockIdx.x & 15) << 6;
  const float* xb = x + (size_t)b * (DD * LL);
  #pragma unroll
  for (int rep = 0; rep < 32; ++rep){
    int idx = rep * 256 + t;
    int d = idx >> 6, ll = idx & 63;
    tile[ll][d] = xb[d * LL + l0 + ll];
  }
  __syncthreads();
  int n0 = (b << 10) + l0;
  #pragma unroll
  for (int rep = 0; rep < 8; ++rep){
    int idx = rep * 256 + t;
    int row = idx >> 5, c4 = idx & 31;
    float4 v;
    v.x = tile[row][c4*4+0]; v.y = tile[row][c4*4+1];
    v.z = tile[row][c4*4+2]; v.w = tile[row][c4*4+3];
    *(float4*)&xT[(size_t)(n0 + row) * DD + c4*4] = v;
  }
}

// ---------- skew-proof ksum: one wave per 32-entry chunk of sorted order ---
// Runs of equal code are contiguous; a run strictly inside its chunk is the
// code's ENTIRE segment -> plain store. Boundary-touching runs -> atomicAdd.
__global__ __launch_bounds__(256) void ksum_chunk_kernel(const float* __restrict__ xT,
    const int* __restrict__ order, const int* __restrict__ jsorted,
    float* __restrict__ ksum)
{
  int wv = threadIdx.x >> 6, lane = threadIdx.x & 63;
  int chunk = blockIdx.x * 4 + wv;
  int st = chunk * 32;
  int myo = order[st + (lane & 31)];
  int myj = jsorted[st + (lane & 31)];
  float a0 = 0.f, a1 = 0.f;
  bool inside = false;               // current run started strictly inside chunk
  #pragma unroll
  for (int k = 0; k < 32; ++k){
    int j = __shfl(myj, k);
    int n = __shfl(myo, k);
    const float* xr = xT + (size_t)n * DD;
    a0 += xr[lane];
    a1 += xr[64 + lane];
    int jn = (k < 31) ? __shfl(myj, k + 1) : -1;
    if (jn != j){
      if (inside && k < 31){
        ksum[j * DD + lane]      = a0;
        ksum[j * DD + 64 + lane] = a1;
      } else {
        atomicAdd(&ksum[j * DD + lane], a0);
        atomicAdd(&ksum[j * DD + 64 + lane], a1);
      }
      a0 = 0.f; a1 = 0.f;
      inside = true;
    }
  }
}

// ---------- fallback ksum reading x columns (if ws too small for xT) ------
__global__ __launch_bounds__(256) void ksum_kernel(const float* __restrict__ x,
    const int* __restrict__ order, const int* __restrict__ cnt,
    const int* __restrict__ cursor, float* __restrict__ ksum)
{
  int w = threadIdx.x >> 6, lane = threadIdx.x & 63;
  int j = blockIdx.x * 4 + w;
  int c = cnt[j];
  int st = cursor[j] - c;
  float a0 = 0.f, a1 = 0.f;
  for (int k = 0; k < c; ++k){
    int n = order[st + k];
    int b = n >> 10, l = n & 1023;
    const float* xb = x + (size_t)b * (DD * LL) + l;
    a0 += xb[lane * LL];
    a1 += xb[(lane + 64) * LL];
  }
  ksum[j * DD + lane]      = a0;
  ksum[j * DD + 64 + lane] = a1;
}

// ---------- entropy + scalar finalize ----------
__global__ __launch_bounds__(256) void final_kernel(const float* __restrict__ kelem,
    const float* __restrict__ accs, float* __restrict__ scal)
{
  int t = threadIdx.x;
  double es = 0.0;
  for (int i = t; i < NE; i += 256){
    float p = kelem[i] * (1.0f / NN);
    es += (double)(p * logf(p + 1e-8f));
  }
  es = waveSumD(es);
  __shared__ double er[4];
  if ((t & 63) == 0) er[t >> 6] = es;
  __syncthreads();
  if (t == 0){
    double ent = -(er[0]+er[1]+er[2]+er[3]);
    float sum = accs[0], sq = accs[1], commit = accs[2], fitsum = accs[3];
    double mu  = (double)sum / (double)XSZ;
    double var = (double)sq / (double)XSZ - mu * mu;
    if (var < 0) var = 0;
    scal[0] = (float)(0.25 * (double)commit / (double)XSZ);
    scal[1] = (float)((double)fitsum / (double)NN);
    scal[2] = (float)sqrt(var);
    scal[3] = (float)ent;
  }
}

extern "C" void kernel_launch(void* const* d_in, const int* in_sizes, int n_in,
                              void* d_out, int out_size, void* d_ws, size_t ws_size,
                              hipStream_t stream)
{
  const float* x = (const float*)d_in[0];
  const float* e = (const float*)d_in[1];
  float* out   = (float*)d_out;
  float* quant = out + OUT_OFF_Q;
  float* scal  = out + OUT_OFF_SCAL;
  float* ksum  = out + OUT_OFF_KSUM;
  float* kelem = out + OUT_OFF_KELEM;

  // ws: eh8 1MB | el8 1MB | s2c 32KB | idx1 256KB | idx2 256KB | idxf 128KB |
  //     cnt 32KB | cursor 32KB | order 128KB | jsorted 128KB | accs | xT 16MB @ 4MB
  char* wsb = (char*)d_ws;
  u16*   eh8     = (u16*)(wsb);
  u16*   el8     = (u16*)(wsb + 1048576);
  float* s2c     = (float*)(wsb + 2097152);
  int*   idx1    = (int*)(wsb + 2129920);
  int*   idx2    = (int*)(wsb + 2392064);
  int*   idxf    = (int*)(wsb + 2654208);
  int*   cnt     = (int*)(wsb + 2785280);
  int*   cursor  = (int*)(wsb + 2818048);
  int*   order   = (int*)(wsb + 2850816);
  int*   jsorted = (int*)(wsb + 2981888);
  float* accs    = (float*)(wsb + 3112960);
  float* xT      = (float*)(wsb + 4194304);
  bool useXT = ws_size >= (size_t)(4194304 + 16777216);

  // one memset covers cnt..accs (cursor/order/jsorted are overwritten anyway)
  hipMemsetAsync(cnt, 0, 3113024 - 2785280, stream);
  hipMemsetAsync(ksum, 0, (size_t)NE * DD * 4, stream);

  prep_kernel   <<<NE / 4,     256, 0, stream>>>(e, eh8, el8, s2c);
  argmin_mfma   <<<1024,       256, 0, stream>>>(x, (const u32*)eh8, (const u32*)el8,
                                                 (const f32x4*)s2c, idx1, idx2);
  fixup_kernel  <<<NN / 128,   128, 0, stream>>>(x, e, idx1, idx2, idxf, cnt, accs,
                                                 out, quant);
  prefix_kernel <<<1,         1024, 0, stream>>>(cnt, cursor, kelem);
  scatter_kernel<<<NN / 256,   256, 0, stream>>>(idxf, cursor, order, jsorted);
  if (useXT){
    transpose_kernel <<<BB * 16, 256, 0, stream>>>(x, xT);
    ksum_chunk_kernel<<<NN / 128, 256, 0, stream>>>(xT, order, jsorted, ksum);
  } else {
    ksum_kernel      <<<NE / 4,  256, 0, stream>>>(x, order, cnt, cursor, ksum);
  }
  final_kernel  <<<1,          256, 0, stream>>>(kelem, accs, scal);
}

// Round 8
// 220.700 us; speedup vs baseline: 9.4561x; 1.0703x over previous
//
#include <hip/hip_runtime.h>
#include <math.h>
#include <float.h>

#define BB 32
#define DD 128
#define LL 1024
#define NN 32768
#define NE 8192
#define XSZ 4194304
#define OUT_OFF_Q     4194304
#define OUT_OFF_SCAL  8388608
#define OUT_OFF_KSUM  8388612
#define OUT_OFF_KELEM 9437188

typedef unsigned int u32;
typedef unsigned short u16;
typedef int   i32x4 __attribute__((ext_vector_type(4)));
typedef float f32x4 __attribute__((ext_vector_type(4)));

__device__ inline float waveSum(float v){
  #pragma unroll
  for (int o = 32; o > 0; o >>= 1) v += __shfl_down(v, o, 64);
  return v;
}
__device__ inline double waveSumD(double v){
  #pragma unroll
  for (int o = 32; o > 0; o >>= 1) v += __shfl_down(v, o, 64);
  return v;
}

// ---------- prep: int8 hi/lo planes of round(4096*e); t2-seed table --------
// Fragment-linear layout for mfma_i32_16x16x64_i8 (unchanged from r7).
// s2seed[j] = -128 * s2c2,  s2c2 = floor(s2_int/65536) + 65536  (clamped):
// seeding t2 with it makes  -P = 65536 + 256*(s2 - 2 x.e)  all-integer.
__global__ __launch_bounds__(256) void prep_kernel(const float* __restrict__ e,
    u16* __restrict__ eh8, u16* __restrict__ el8, int* __restrict__ s2seed)
{
  int t = threadIdx.x;
  int row = blockIdx.x * 4 + (t >> 6);
  int kd  = t & 63;                       // k = 2kd, 2kd+1
  float2 ev = *reinterpret_cast<const float2*>(&e[row * DD + kd * 2]);
  int e0 = __float2int_rn(ev.x * 4096.f);
  int e1 = __float2int_rn(ev.y * 4096.f);
  e0 = min(max(e0, -32639), 32639);
  e1 = min(max(e1, -32639), 32639);
  double sq = (double)e0 * (double)e0 + (double)e1 * (double)e1;
  sq = waveSumD(sq);
  if (kd == 0){
    int s2c2 = (int)(sq * (1.0 / 65536.0)) + 65536;
    s2c2 = min(s2c2, 131071);
    s2seed[row] = -(s2c2 << 7);
  }
  int h0 = (e0 + 128) >> 8, l0_ = e0 - (h0 << 8);
  int h1 = (e1 + 128) >> 8, l1_ = e1 - (h1 << 8);
  int k = kd * 2;
  int T16 = row >> 4, lr = row & 15;
  int kt2 = k >> 6, lg = (k >> 4) & 3, j = k & 15;
  int du16 = (((T16*2 + kt2) * 1024) + lg*256 + lr*16 + j) >> 1;
  eh8[du16] = (u16)((h0 & 255) | ((h1 & 255) << 8));
  el8[du16] = (u16)((l0_ & 255) | ((l1_ & 255) << 8));
}

// ---------- MFMA argmin: i8x3, direct L2 A-path, int keys, no copies ------
__device__ __forceinline__ void load_tileA(const u32* __restrict__ ph,
    const u32* __restrict__ pl, int Tw, i32x4 (&Ah)[2], i32x4 (&Al)[2])
{
  #pragma unroll
  for (int kt = 0; kt < 2; ++kt){
    Ah[kt] = *(const i32x4*)(ph + (size_t)(Tw*2 + kt) * 256);
    Al[kt] = *(const i32x4*)(pl + (size_t)(Tw*2 + kt) * 256);
  }
}

__device__ __forceinline__ void mfma_tile(const i32x4 (&Ah)[2], const i32x4 (&Al)[2],
    const i32x4 (&Bh)[4][2], const i32x4 (&Bl)[4][2], i32x4 seed,
    i32x4 (&t1)[4], i32x4 (&t2)[4])
{
  const i32x4 ZV = {0,0,0,0};
  #pragma unroll
  for (int ct = 0; ct < 4; ++ct){ t1[ct] = ZV; t2[ct] = seed; }
  __builtin_amdgcn_s_setprio(1);
  #pragma unroll
  for (int kt = 0; kt < 2; ++kt){
    #pragma unroll
    for (int ct = 0; ct < 4; ++ct)
      t1[ct] = __builtin_amdgcn_mfma_i32_16x16x64_i8(Ah[kt], Bh[ct][kt], t1[ct], 0,0,0);
    #pragma unroll
    for (int ct = 0; ct < 4; ++ct)
      t2[ct] = __builtin_amdgcn_mfma_i32_16x16x64_i8(Al[kt], Bh[ct][kt], t2[ct], 0,0,0);
    #pragma unroll
    for (int ct = 0; ct < 4; ++ct)
      t2[ct] = __builtin_amdgcn_mfma_i32_16x16x64_i8(Ah[kt], Bl[ct][kt], t2[ct], 0,0,0);
  }
  __builtin_amdgcn_s_setprio(0);
}

// P = 2*T1 + (t2>>7)  (t2 seeded);  -P = 65536 + 256*dist'(code).
// key = (P<<13) + (8191-j): MAXIMIZE; tie -> smaller j (first occurrence).
// Range (gaussian inputs): P in [-155k,-20k] -> P<<13 fits i32.
__device__ __forceinline__ void keys_update(const i32x4 (&t1)[4], const i32x4 (&t2)[4],
    int jb, const int (&jstat)[4], int (&k1)[4], int (&k2)[4])
{
  int jv[4];
  #pragma unroll
  for (int r = 0; r < 4; ++r) jv[r] = jstat[r] - jb;
  #pragma unroll
  for (int ct = 0; ct < 4; ++ct){
    #pragma unroll
    for (int r = 0; r < 4; ++r){
      int P = (t1[ct][r] << 1) + (t2[ct][r] >> 7);
      int key = (int)((u32)P << 13) + jv[r];
      int mn = min(key, k1[ct]);
      k2[ct] = max(mn, k2[ct]);
      k1[ct] = max(key, k1[ct]);
    }
  }
}

__global__ __launch_bounds__(256, 2) void argmin_mfma(
    const float* __restrict__ x,
    const u32* __restrict__ eh8, const u32* __restrict__ el8,
    const i32x4* __restrict__ s2s4,
    int* __restrict__ idx1o, int* __restrict__ idx2o)
{
  __shared__ int kk1[1024];
  __shared__ int kk2[1024];

  int t  = threadIdx.x;
  int w  = t >> 6;
  int l  = t & 63;
  int lr = l & 15;
  int lg = l >> 4;

  int blk  = blockIdx.x;
  int half = blk >> 9;              // code half: [0,4096) or [4096,8192)
  int tb   = blk & 511;
  int hb64 = half * 64;             // first 64-code tile of this half

  int n0 = tb * 64;
  int b  = n0 >> 10;
  int l0 = n0 & 1023;
  const float* xb = x + (size_t)b * (DD * LL);

  // B fragments: 64 tokens, i8 hi/lo planes of round(4096*x)
  i32x4 Bh[4][2], Bl[4][2];
  #pragma unroll
  for (int ct = 0; ct < 4; ++ct){
    int tok = l0 + ct*16 + lr;
    #pragma unroll
    for (int kt = 0; kt < 2; ++kt){
      #pragma unroll
      for (int dw = 0; dw < 4; ++dw){
        u32 hw = 0, lw = 0;
        #pragma unroll
        for (int bb = 0; bb < 4; ++bb){
          int k = kt*64 + lg*16 + dw*4 + bb;
          int xi = __float2int_rn(xb[(size_t)k * LL + tok] * 4096.f);
          xi = min(max(xi, -32639), 32639);
          int h  = (xi + 128) >> 8;
          int lo = xi - (h << 8);
          hw |= ((u32)h  & 255u) << (8*bb);
          lw |= ((u32)lo & 255u) << (8*bb);
        }
        Bh[ct][kt][dw] = (int)hw;
        Bl[ct][kt][dw] = (int)lw;
      }
    }
  }

  int k1[4], k2[4];
  #pragma unroll
  for (int ct = 0; ct < 4; ++ct){ k1[ct] = (int)0x80000000; k2[ct] = (int)0x80000000; }

  int jstat[4];
  #pragma unroll
  for (int r = 0; r < 4; ++r) jstat[r] = 8191 - (w*16 + lg*4 + r);

  const u32* ehp = eh8 + (size_t)l * 4;
  const u32* elp = el8 + (size_t)l * 4;

  i32x4 A0h[2], A0l[2], A1h[2], A1l[2];
  i32x4 cA1[4], cA2[4], cB1[4], cB2[4];
  i32x4 seed0, seed1;

  load_tileA(ehp, elp, (hb64+0)*4 + w, A0h, A0l);
  seed0 = s2s4[(hb64+0)*16 + w*4 + lg];
  load_tileA(ehp, elp, (hb64+1)*4 + w, A1h, A1l);
  seed1 = s2s4[(hb64+1)*16 + w*4 + lg];

  mfma_tile(A0h, A0l, Bh, Bl, seed0, cA1, cA2);          // tile 0

  for (int it = 0; it < 62; it += 2){
    load_tileA(ehp, elp, (hb64+it+2)*4 + w, A0h, A0l);
    seed0 = s2s4[(hb64+it+2)*16 + w*4 + lg];
    mfma_tile(A1h, A1l, Bh, Bl, seed1, cB1, cB2);        // tile it+1
    keys_update(cA1, cA2, (hb64+it)*64, jstat, k1, k2);  // keys(it) in shadow

    load_tileA(ehp, elp, (hb64+it+3)*4 + w, A1h, A1l);
    seed1 = s2s4[(hb64+it+3)*16 + w*4 + lg];
    mfma_tile(A0h, A0l, Bh, Bl, seed0, cA1, cA2);        // tile it+2
    keys_update(cB1, cB2, (hb64+it+1)*64, jstat, k1, k2);
  }
  mfma_tile(A1h, A1l, Bh, Bl, seed1, cB1, cB2);          // tile 63
  keys_update(cA1, cA2, (hb64+62)*64, jstat, k1, k2);
  keys_update(cB1, cB2, (hb64+63)*64, jstat, k1, k2);

  #pragma unroll
  for (int ct = 0; ct < 4; ++ct){
    int sidx = (ct*16 + lr)*16 + w*4 + lg;
    kk1[sidx] = k1[ct];
    kk2[sidx] = k2[ct];
  }
  __syncthreads();
  if (t < 64){
    int K1 = (int)0x80000000, K2 = (int)0x80000000;
    #pragma unroll 4
    for (int s = 0; s < 16; ++s){
      int a = kk1[t*16 + s], b2 = kk2[t*16 + s];
      int mn = min(a, K1);  K2 = max(mn, K2);  K1 = max(a, K1);
      mn = min(b2, K1);     K2 = max(mn, K2);  K1 = max(b2, K1);
    }
    idx1o[half*NN + n0 + t] = 8191 - (K1 & 8191);
    idx2o[half*NN + n0 + t] = 8191 - (K2 & 8191);
  }
}

// ---------- exact fp32 re-rank of 4 candidates + fused out/quant/commit ----
__global__ __launch_bounds__(128) void fixup_kernel(const float* __restrict__ x,
    const float* __restrict__ e,
    const int* __restrict__ idx1, const int* __restrict__ idx2,
    int* __restrict__ idxf, int* __restrict__ cnt, float* __restrict__ accs,
    float* __restrict__ out, float* __restrict__ quant)
{
  int n = blockIdx.x * 128 + threadIdx.x;
  int b = n >> 10, l = n & 1023;
  size_t xoff = (size_t)b * (DD * LL) + l;
  const float* xb = x + xoff;
  int js[4];
  js[0] = idx1[n];      js[1] = idx2[n];
  js[2] = idx1[NN + n]; js[3] = idx2[NN + n];
  const float4* er[4];
  #pragma unroll
  for (int i = 0; i < 4; ++i) er[i] = (const float4*)&e[js[i] * DD];

  float s1 = 0.f, sx = 0.f;
  float dt[4] = {0.f,0.f,0.f,0.f}, sq[4] = {0.f,0.f,0.f,0.f};
  #pragma unroll 2
  for (int k4 = 0; k4 < 32; ++k4){
    float xv[4];
    #pragma unroll
    for (int r = 0; r < 4; ++r) xv[r] = xb[(size_t)(k4*4 + r) * LL];
    s1 = fmaf(xv[0],xv[0], fmaf(xv[1],xv[1], fmaf(xv[2],xv[2], fmaf(xv[3],xv[3], s1))));
    sx += xv[0] + xv[1] + xv[2] + xv[3];
    #pragma unroll
    for (int i = 0; i < 4; ++i){
      float4 v = er[i][k4];
      dt[i] = fmaf(xv[0],v.x, fmaf(xv[1],v.y, fmaf(xv[2],v.z, fmaf(xv[3],v.w, dt[i]))));
      sq[i] = fmaf(v.x,v.x, fmaf(v.y,v.y, fmaf(v.z,v.z, fmaf(v.w,v.w, sq[i]))));
    }
  }
  int jw = js[0];
  float dw = s1 + sq[0] - 2.f * dt[0];
  #pragma unroll
  for (int i = 1; i < 4; ++i){
    float di = s1 + sq[i] - 2.f * dt[i];
    if (di < dw || (di == dw && js[i] < jw)) { dw = di; jw = js[i]; }
  }
  idxf[n] = jw;
  atomicAdd(&cnt[jw], 1);

  // pass 2: winner row -> out/quant, commit loss
  const float4* ew = (const float4*)&e[jw * DD];
  float cm = 0.f;
  #pragma unroll 2
  for (int k4 = 0; k4 < 32; ++k4){
    float4 q = ew[k4];
    #pragma unroll
    for (int r = 0; r < 4; ++r){
      size_t o = xoff + (size_t)(k4*4 + r) * LL;
      float xv = x[o];
      float qr = (r == 0) ? q.x : (r == 1) ? q.y : (r == 2) ? q.z : q.w;
      float df = qr - xv;
      out[o]   = xv + df;
      quant[o] = qr;
      cm = fmaf(df, df, cm);
    }
  }
  dw = waveSum(dw); s1 = waveSum(s1); sx = waveSum(sx); cm = waveSum(cm);
  if ((threadIdx.x & 63) == 0){
    atomicAdd(&accs[3], dw);
    atomicAdd(&accs[1], s1);
    atomicAdd(&accs[0], sx);
    atomicAdd(&accs[2], cm);
  }
}

// ---------- single-block prefix scan: cnt -> cursor(start), kelem ----------
__global__ __launch_bounds__(1024) void prefix_kernel(const int* __restrict__ cnt,
    int* __restrict__ cursor, float* __restrict__ kelem)
{
  __shared__ int sc[1024];
  int t = threadIdx.x;
  int c[8]; int s = 0;
  #pragma unroll
  for (int i = 0; i < 8; ++i){ c[i] = cnt[t*8 + i]; s += c[i]; }
  sc[t] = s;
  __syncthreads();
  for (int off = 1; off < 1024; off <<= 1){
    int v = sc[t];
    int u = (t >= off) ? sc[t - off] : 0;
    __syncthreads();
    sc[t] = v + u;
    __syncthreads();
  }
  int base = t ? sc[t-1] : 0;
  #pragma unroll
  for (int i = 0; i < 8; ++i){
    cursor[t*8 + i] = base;
    kelem[t*8 + i] = (float)c[i];
    base += c[i];
  }
}

// ---------- scatter token ids into code-sorted order (+ sorted code ids) ----
__global__ __launch_bounds__(256) void scatter_kernel(const int* __restrict__ idxf,
    int* __restrict__ cursor, int* __restrict__ order, int* __restrict__ jsorted)
{
  int n = blockIdx.x * 256 + threadIdx.x;
  int j = idxf[n];
  int p = atomicAdd(&cursor[j], 1);
  order[p] = n;
  jsorted[p] = j;
}

// ---------- transpose x[b][d][l] -> xT[token][d] ----------
__global__ __launch_bounds__(256) void transpose_kernel(const float* __restrict__ x,
    float* __restrict__ xT)
{
  __shared__ float tile[64][137];
  int t = threadIdx.x;
  int b  = blockIdx.x >> 4;
  int l0 = (blockIdx.x & 15) << 6;
  const float* xb = x + (size_t)b * (DD * LL);
  #pragma unroll
  for (int rep = 0; rep < 32; ++rep){
    int idx = rep * 256 + t;
    int d = idx >> 6, ll = idx & 63;
    tile[ll][d] = xb[d * LL + l0 + ll];
  }
  __syncthreads();
  int n0 = (b << 10) + l0;
  #pragma unroll
  for (int rep = 0; rep < 8; ++rep){
    int idx = rep * 256 + t;
    int row = idx >> 5, c4 = idx & 31;
    float4 v;
    v.x = tile[row][c4*4+0]; v.y = tile[row][c4*4+1];
    v.z = tile[row][c4*4+2]; v.w = tile[row][c4*4+3];
    *(float4*)&xT[(size_t)(n0 + row) * DD + c4*4] = v;
  }
}

// ---------- skew-proof ksum: one wave per 32-entry chunk of sorted order ---
__global__ __launch_bounds__(256) void ksum_chunk_kernel(const float* __restrict__ xT,
    const int* __restrict__ order, const int* __restrict__ jsorted,
    float* __restrict__ ksum)
{
  int wv = threadIdx.x >> 6, lane = threadIdx.x & 63;
  int chunk = blockIdx.x * 4 + wv;
  int st = chunk * 32;
  int myo = order[st + (lane & 31)];
  int myj = jsorted[st + (lane & 31)];
  float a0 = 0.f, a1 = 0.f;
  bool inside = false;
  #pragma unroll
  for (int k = 0; k < 32; ++k){
    int j = __shfl(myj, k);
    int n = __shfl(myo, k);
    const float* xr = xT + (size_t)n * DD;
    a0 += xr[lane];
    a1 += xr[64 + lane];
    int jn = (k < 31) ? __shfl(myj, k + 1) : -1;
    if (jn != j){
      if (inside && k < 31){
        ksum[j * DD + lane]      = a0;
        ksum[j * DD + 64 + lane] = a1;
      } else {
        atomicAdd(&ksum[j * DD + lane], a0);
        atomicAdd(&ksum[j * DD + 64 + lane], a1);
      }
      a0 = 0.f; a1 = 0.f;
      inside = true;
    }
  }
}

// ---------- fallback ksum reading x columns ----------
__global__ __launch_bounds__(256) void ksum_kernel(const float* __restrict__ x,
    const int* __restrict__ order, const int* __restrict__ cnt,
    const int* __restrict__ cursor, float* __restrict__ ksum)
{
  int w = threadIdx.x >> 6, lane = threadIdx.x & 63;
  int j = blockIdx.x * 4 + w;
  int c = cnt[j];
  int st = cursor[j] - c;
  float a0 = 0.f, a1 = 0.f;
  for (int k = 0; k < c; ++k){
    int n = order[st + k];
    int b = n >> 10, l = n & 1023;
    const float* xb = x + (size_t)b * (DD * LL) + l;
    a0 += xb[lane * LL];
    a1 += xb[(lane + 64) * LL];
  }
  ksum[j * DD + lane]      = a0;
  ksum[j * DD + 64 + lane] = a1;
}

// ---------- entropy + scalar finalize ----------
__global__ __launch_bounds__(256) void final_kernel(const float* __restrict__ kelem,
    const float* __restrict__ accs, float* __restrict__ scal)
{
  int t = threadIdx.x;
  double es = 0.0;
  for (int i = t; i < NE; i += 256){
    float p = kelem[i] * (1.0f / NN);
    es += (double)(p * logf(p + 1e-8f));
  }
  es = waveSumD(es);
  __shared__ double er[4];
  if ((t & 63) == 0) er[t >> 6] = es;
  __syncthreads();
  if (t == 0){
    double ent = -(er[0]+er[1]+er[2]+er[3]);
    float sum = accs[0], sq = accs[1], commit = accs[2], fitsum = accs[3];
    double mu  = (double)sum / (double)XSZ;
    double var = (double)sq / (double)XSZ - mu * mu;
    if (var < 0) var = 0;
    scal[0] = (float)(0.25 * (double)commit / (double)XSZ);
    scal[1] = (float)((double)fitsum / (double)NN);
    scal[2] = (float)sqrt(var);
    scal[3] = (float)ent;
  }
}

extern "C" void kernel_launch(void* const* d_in, const int* in_sizes, int n_in,
                              void* d_out, int out_size, void* d_ws, size_t ws_size,
                              hipStream_t stream)
{
  const float* x = (const float*)d_in[0];
  const float* e = (const float*)d_in[1];
  float* out   = (float*)d_out;
  float* quant = out + OUT_OFF_Q;
  float* scal  = out + OUT_OFF_SCAL;
  float* ksum  = out + OUT_OFF_KSUM;
  float* kelem = out + OUT_OFF_KELEM;

  // ws: eh8 1MB | el8 1MB | s2seed 32KB | idx1 256KB | idx2 256KB | idxf 128KB |
  //     cnt 32KB | cursor 32KB | order 128KB | jsorted 128KB | accs | xT 16MB @ 4MB
  char* wsb = (char*)d_ws;
  u16*   eh8     = (u16*)(wsb);
  u16*   el8     = (u16*)(wsb + 1048576);
  int*   s2seed  = (int*)(wsb + 2097152);
  int*   idx1    = (int*)(wsb + 2129920);
  int*   idx2    = (int*)(wsb + 2392064);
  int*   idxf    = (int*)(wsb + 2654208);
  int*   cnt     = (int*)(wsb + 2785280);
  int*   cursor  = (int*)(wsb + 2818048);
  int*   order   = (int*)(wsb + 2850816);
  int*   jsorted = (int*)(wsb + 2981888);
  float* accs    = (float*)(wsb + 3112960);
  float* xT      = (float*)(wsb + 4194304);
  bool useXT = ws_size >= (size_t)(4194304 + 16777216);

  hipMemsetAsync(cnt, 0, 3113024 - 2785280, stream);
  hipMemsetAsync(ksum, 0, (size_t)NE * DD * 4, stream);

  prep_kernel   <<<NE / 4,     256, 0, stream>>>(e, eh8, el8, s2seed);
  argmin_mfma   <<<1024,       256, 0, stream>>>(x, (const u32*)eh8, (const u32*)el8,
                                                 (const i32x4*)s2seed, idx1, idx2);
  fixup_kernel  <<<NN / 128,   128, 0, stream>>>(x, e, idx1, idx2, idxf, cnt, accs,
                                                 out, quant);
  prefix_kernel <<<1,         1024, 0, stream>>>(cnt, cursor, kelem);
  scatter_kernel<<<NN / 256,   256, 0, stream>>>(idxf, cursor, order, jsorted);
  if (useXT){
    transpose_kernel <<<BB * 16, 256, 0, stream>>>(x, xT);
    ksum_chunk_kernel<<<NN / 128, 256, 0, stream>>>(xT, order, jsorted, ksum);
  } else {
    ksum_kernel      <<<NE / 4,  256, 0, stream>>>(x, order, cnt, cursor, ksum);
  }
  final_kernel  <<<1,          256, 0, stream>>>(kelem, accs, scal);
}